// Round 1
// baseline (1263.263 us; speedup 1.0000x reference)
//
#include <hip/hip_runtime.h>

#define N_NODES 100000
#define N_EDGES 1600000
#define N_GRAPHS 128

// ---------------- K1: degree histograms ----------------
__global__ void k_degrees(const int* __restrict__ src, const int* __restrict__ dst,
                          float* __restrict__ deg_out, float* __restrict__ deg_in) {
  int e = blockIdx.x * blockDim.x + threadIdx.x;
  if (e < N_EDGES) {
    atomicAdd(&deg_out[src[e]], 1.0f);
    atomicAdd(&deg_in[dst[e]], 1.0f);
  }
}

// ---------------- K2: norms + per-graph node counts ----------------
__global__ void k_norms(float* __restrict__ deg_out, float* __restrict__ deg_in,
                        const int* __restrict__ gid, float* __restrict__ counts) {
  int i = blockIdx.x * blockDim.x + threadIdx.x;
  if (i < N_NODES) {
    deg_out[i] = rsqrtf(fmaxf(deg_out[i], 1.0f));   // becomes norm_out
    deg_in[i]  = rsqrtf(fmaxf(deg_in[i], 1.0f));    // becomes norm_in
    atomicAdd(&counts[gid[i]], 1.0f);
  }
}

// ---------------- K3: h1 = (x * norm_out) @ W1   [N,128]x[128,64] ----------------
__global__ __launch_bounds__(256) void k_gemm1(const float* __restrict__ x,
                                               const float* __restrict__ W1,
                                               const float* __restrict__ norm_out,
                                               float* __restrict__ h1) {
  __shared__ float Wt[128 * 64];   // 32 KB
  __shared__ float xt[32 * 128];   // 16 KB
  const int t = threadIdx.x;
  const int row0 = blockIdx.x * 32;

  // stage W1 (8192 floats) as float4
  const float4* W4 = (const float4*)W1;
  float4* Wt4 = (float4*)Wt;
  #pragma unroll
  for (int i = 0; i < 8; ++i) Wt4[t + 256 * i] = W4[t + 256 * i];

  // stage 32 rows of x, pre-scaled by norm_out
  const float4* x4 = (const float4*)(x + (size_t)row0 * 128);
  float4* xt4 = (float4*)xt;
  #pragma unroll
  for (int i = 0; i < 4; ++i) {
    int idx = t + 256 * i;            // 1024 float4 total, 32 per row
    int r = idx >> 5;
    float s = norm_out[row0 + r];
    float4 v = x4[idx];
    v.x *= s; v.y *= s; v.z *= s; v.w *= s;
    xt4[idx] = v;
  }
  __syncthreads();

  const int col = t & 63;       // 0..63
  const int ty  = t >> 6;       // 0..3 -> rows ty*8..ty*8+7
  float acc[8] = {0.f,0.f,0.f,0.f,0.f,0.f,0.f,0.f};
  for (int k = 0; k < 128; ++k) {
    float wv = Wt[k * 64 + col];
    #pragma unroll
    for (int i = 0; i < 8; ++i)
      acc[i] += xt[(ty * 8 + i) * 128 + k] * wv;
  }
  #pragma unroll
  for (int i = 0; i < 8; ++i)
    h1[(size_t)(row0 + ty * 8 + i) * 64 + col] = acc[i];
}

// ---------------- K4: edge scatter-add, 64 feats ----------------
__global__ void k_scatter1(const int* __restrict__ src, const int* __restrict__ dst,
                           const float* __restrict__ h1, float* __restrict__ agg1) {
  int tid = blockIdx.x * blockDim.x + threadIdx.x;
  int e = tid >> 6;
  int f = tid & 63;
  if (e < N_EDGES) {
    int s = src[e], d = dst[e];
    atomicAdd(&agg1[(size_t)d * 64 + f], h1[(size_t)s * 64 + f]);
  }
}

// ---------------- K5: h1r = relu(agg1 * norm_in + b1) ----------------
__global__ void k_finish1(const float* __restrict__ agg1, const float* __restrict__ norm_in,
                          const float* __restrict__ b1, float* __restrict__ h1) {
  int i = blockIdx.x * blockDim.x + threadIdx.x;
  if (i < N_NODES * 64) {
    int node = i >> 6, j = i & 63;
    float v = agg1[i] * norm_in[node] + b1[j];
    h1[i] = fmaxf(v, 0.0f);
  }
}

// ---------------- K6: h2 = (h1r * norm_out) @ W2   [N,64]x[64,16] ----------------
__global__ __launch_bounds__(256) void k_gemm2(const float* __restrict__ h1r,
                                               const float* __restrict__ W2,
                                               const float* __restrict__ norm_out,
                                               float* __restrict__ h2) {
  __shared__ float Wt[64 * 16];
  __shared__ float xt[64 * 65];   // padded: rows differ in bank
  const int t = threadIdx.x;
  const int row0 = blockIdx.x * 64;

  for (int i = t; i < 64 * 16; i += 256) Wt[i] = W2[i];
  for (int i = t; i < 64 * 64; i += 256) {
    int r = i >> 6, c = i & 63;
    int row = row0 + r;
    float v = 0.f;
    if (row < N_NODES) v = h1r[(size_t)row * 64 + c] * norm_out[row];
    xt[r * 65 + c] = v;
  }
  __syncthreads();

  const int col = t & 15;     // 0..15
  const int rg  = t >> 4;     // 0..15 -> rows rg*4..rg*4+3
  float acc[4] = {0.f, 0.f, 0.f, 0.f};
  for (int k = 0; k < 64; ++k) {
    float wv = Wt[k * 16 + col];
    #pragma unroll
    for (int i = 0; i < 4; ++i)
      acc[i] += xt[(rg * 4 + i) * 65 + k] * wv;
  }
  #pragma unroll
  for (int i = 0; i < 4; ++i) {
    int row = row0 + rg * 4 + i;
    if (row < N_NODES) h2[(size_t)row * 16 + col] = acc[i];
  }
}

// ---------------- K7: edge scatter-add, 16 feats ----------------
__global__ void k_scatter2(const int* __restrict__ src, const int* __restrict__ dst,
                           const float* __restrict__ h2, float* __restrict__ agg2) {
  int tid = blockIdx.x * blockDim.x + threadIdx.x;
  int e = tid >> 4;
  int f = tid & 15;
  if (e < N_EDGES) {
    int s = src[e], d = dst[e];
    atomicAdd(&agg2[(size_t)d * 16 + f], h2[(size_t)s * 16 + f]);
  }
}

// ---------------- K8: scale+bias then pool-sum into d_out ----------------
__global__ void k_finish2(const float* __restrict__ agg2, const float* __restrict__ norm_in,
                          const float* __restrict__ b2, const int* __restrict__ gid,
                          float* __restrict__ out) {
  int i = blockIdx.x * blockDim.x + threadIdx.x;
  if (i < N_NODES * 16) {
    int node = i >> 4, j = i & 15;
    float v = agg2[i] * norm_in[node] + b2[j];
    atomicAdd(&out[gid[node] * 16 + j], v);
  }
}

// ---------------- K9: divide by counts ----------------
__global__ void k_div(float* __restrict__ out, const float* __restrict__ counts) {
  int i = blockIdx.x * blockDim.x + threadIdx.x;
  if (i < N_GRAPHS * 16) {
    int g = i >> 4;
    out[i] /= fmaxf(counts[g], 1.0f);
  }
}

extern "C" void kernel_launch(void* const* d_in, const int* in_sizes, int n_in,
                              void* d_out, int out_size, void* d_ws, size_t ws_size,
                              hipStream_t stream) {
  const float* x   = (const float*)d_in[0];
  const float* W1  = (const float*)d_in[1];
  const float* b1  = (const float*)d_in[2];
  const float* W2  = (const float*)d_in[3];
  const float* b2  = (const float*)d_in[4];
  const int*   src = (const int*)d_in[5];
  const int*   dst = (const int*)d_in[6];
  const int*   gid = (const int*)d_in[7];
  float* out = (float*)d_out;

  // workspace layout (floats):
  //   [0, 64N)        agg1   (later reused: h2 = [0,16N), agg2 = [16N,32N))
  //   [64N, 65N)      deg_out -> norm_out
  //   [65N, 66N)      deg_in  -> norm_in
  //   [66N, 66N+G)    counts
  //   [66N+G, 130N+G) h1
  float* ws      = (float*)d_ws;
  float* agg1    = ws;
  float* h2      = ws;                          // reuse after K5
  float* agg2    = ws + (size_t)16 * N_NODES;   // reuse after K5
  float* norm_o  = ws + (size_t)64 * N_NODES;
  float* norm_i  = norm_o + N_NODES;
  float* counts  = norm_i + N_NODES;
  float* h1      = counts + N_GRAPHS;

  // zero: agg1 + degs + counts (contiguous prefix)
  size_t zero_floats = (size_t)66 * N_NODES + N_GRAPHS;
  hipMemsetAsync(d_ws, 0, zero_floats * sizeof(float), stream);
  hipMemsetAsync(d_out, 0, (size_t)out_size * sizeof(float), stream);

  k_degrees <<<(N_EDGES + 255) / 256, 256, 0, stream>>>(src, dst, norm_o, norm_i);
  k_norms   <<<(N_NODES + 255) / 256, 256, 0, stream>>>(norm_o, norm_i, gid, counts);
  k_gemm1   <<<N_NODES / 32, 256, 0, stream>>>(x, W1, norm_o, h1);
  k_scatter1<<<(size_t)N_EDGES * 64 / 256, 256, 0, stream>>>(src, dst, h1, agg1);
  k_finish1 <<<(N_NODES * 64 + 255) / 256, 256, 0, stream>>>(agg1, norm_i, b1, h1);
  // re-zero agg2 region (it aliases old agg1 space)
  hipMemsetAsync(agg2, 0, (size_t)16 * N_NODES * sizeof(float), stream);
  k_gemm2   <<<(N_NODES + 63) / 64, 256, 0, stream>>>(h1, W2, norm_o, h2);
  k_scatter2<<<(size_t)N_EDGES * 16 / 256, 256, 0, stream>>>(src, dst, h2, agg2);
  k_finish2 <<<(N_NODES * 16 + 255) / 256, 256, 0, stream>>>(agg2, norm_i, b2, gid, out);
  k_div     <<<(N_GRAPHS * 16 + 255) / 256, 256, 0, stream>>>(out, counts);
}

// Round 2
// 821.104 us; speedup vs baseline: 1.5385x; 1.5385x over previous
//
#include <hip/hip_runtime.h>

#define N_NODES 100000
#define N_EDGES 1600000
#define N_GRAPHS 128

// ---------------- K1: degree histograms ----------------
__global__ void k_degrees(const int* __restrict__ src, const int* __restrict__ dst,
                          float* __restrict__ deg_out, float* __restrict__ deg_in) {
  int e = blockIdx.x * blockDim.x + threadIdx.x;
  if (e < N_EDGES) {
    atomicAdd(&deg_out[src[e]], 1.0f);
    atomicAdd(&deg_in[dst[e]], 1.0f);
  }
}

// ---------------- K2: norms (no atomics) ----------------
__global__ void k_norms(float* __restrict__ deg_out, float* __restrict__ deg_in) {
  int i = blockIdx.x * blockDim.x + threadIdx.x;
  if (i < N_NODES) {
    deg_out[i] = rsqrtf(fmaxf(deg_out[i], 1.0f));   // becomes norm_out
    deg_in[i]  = rsqrtf(fmaxf(deg_in[i], 1.0f));    // becomes norm_in
  }
}

// ---------------- K3: h1 = (x * norm_out) @ W1   [N,128]x[128,64] ----------------
__global__ __launch_bounds__(256) void k_gemm1(const float* __restrict__ x,
                                               const float* __restrict__ W1,
                                               const float* __restrict__ norm_out,
                                               float* __restrict__ h1) {
  __shared__ float Wt[128 * 64];   // 32 KB
  __shared__ float xt[32 * 128];   // 16 KB
  const int t = threadIdx.x;
  const int row0 = blockIdx.x * 32;

  const float4* W4 = (const float4*)W1;
  float4* Wt4 = (float4*)Wt;
  #pragma unroll
  for (int i = 0; i < 8; ++i) Wt4[t + 256 * i] = W4[t + 256 * i];

  const float4* x4 = (const float4*)(x + (size_t)row0 * 128);
  float4* xt4 = (float4*)xt;
  #pragma unroll
  for (int i = 0; i < 4; ++i) {
    int idx = t + 256 * i;            // 1024 float4 total, 32 per row
    int r = idx >> 5;
    float s = norm_out[row0 + r];
    float4 v = x4[idx];
    v.x *= s; v.y *= s; v.z *= s; v.w *= s;
    xt4[idx] = v;
  }
  __syncthreads();

  const int col = t & 63;       // 0..63
  const int ty  = t >> 6;       // 0..3 -> rows ty*8..ty*8+7
  float acc[8] = {0.f,0.f,0.f,0.f,0.f,0.f,0.f,0.f};
  for (int k = 0; k < 128; ++k) {
    float wv = Wt[k * 64 + col];
    #pragma unroll
    for (int i = 0; i < 8; ++i)
      acc[i] += xt[(ty * 8 + i) * 128 + k] * wv;
  }
  #pragma unroll
  for (int i = 0; i < 8; ++i)
    h1[(size_t)(row0 + ty * 8 + i) * 64 + col] = acc[i];
}

// ---------------- K4: edge scatter-add, 64 feats ----------------
__global__ void k_scatter1(const int* __restrict__ src, const int* __restrict__ dst,
                           const float* __restrict__ h1, float* __restrict__ agg1) {
  int tid = blockIdx.x * blockDim.x + threadIdx.x;
  int e = tid >> 6;
  int f = tid & 63;
  if (e < N_EDGES) {
    int s = src[e], d = dst[e];
    atomicAdd(&agg1[(size_t)d * 64 + f], h1[(size_t)s * 64 + f]);
  }
}

// ---------------- K5: h1r = relu(agg1 * norm_in + b1) ----------------
__global__ void k_finish1(const float* __restrict__ agg1, const float* __restrict__ norm_in,
                          const float* __restrict__ b1, float* __restrict__ h1) {
  int i = blockIdx.x * blockDim.x + threadIdx.x;
  if (i < N_NODES * 64) {
    int node = i >> 6, j = i & 63;
    float v = agg1[i] * norm_in[node] + b1[j];
    h1[i] = fmaxf(v, 0.0f);
  }
}

// ---------------- K6: h2 = (h1r * norm_out) @ W2   [N,64]x[64,16] ----------------
__global__ __launch_bounds__(256) void k_gemm2(const float* __restrict__ h1r,
                                               const float* __restrict__ W2,
                                               const float* __restrict__ norm_out,
                                               float* __restrict__ h2) {
  __shared__ float Wt[64 * 16];
  __shared__ float xt[64 * 65];   // padded
  const int t = threadIdx.x;
  const int row0 = blockIdx.x * 64;

  for (int i = t; i < 64 * 16; i += 256) Wt[i] = W2[i];
  for (int i = t; i < 64 * 64; i += 256) {
    int r = i >> 6, c = i & 63;
    int row = row0 + r;
    float v = 0.f;
    if (row < N_NODES) v = h1r[(size_t)row * 64 + c] * norm_out[row];
    xt[r * 65 + c] = v;
  }
  __syncthreads();

  const int col = t & 15;     // 0..15
  const int rg  = t >> 4;     // 0..15 -> rows rg*4..rg*4+3
  float acc[4] = {0.f, 0.f, 0.f, 0.f};
  for (int k = 0; k < 64; ++k) {
    float wv = Wt[k * 16 + col];
    #pragma unroll
    for (int i = 0; i < 4; ++i)
      acc[i] += xt[(rg * 4 + i) * 65 + k] * wv;
  }
  #pragma unroll
  for (int i = 0; i < 4; ++i) {
    int row = row0 + rg * 4 + i;
    if (row < N_NODES) h2[(size_t)row * 16 + col] = acc[i];
  }
}

// ---------------- K7: edge scatter-add, 16 feats ----------------
__global__ void k_scatter2(const int* __restrict__ src, const int* __restrict__ dst,
                           const float* __restrict__ h2, float* __restrict__ agg2) {
  int tid = blockIdx.x * blockDim.x + threadIdx.x;
  int e = tid >> 4;
  int f = tid & 15;
  if (e < N_EDGES) {
    int s = src[e], d = dst[e];
    atomicAdd(&agg2[(size_t)d * 16 + f], h2[(size_t)s * 16 + f]);
  }
}

// ---------------- K8: per-graph mean pool (no atomics; gid is sorted) ----------------
__global__ __launch_bounds__(256) void k_pool(const float* __restrict__ agg2,
                                              const float* __restrict__ norm_in,
                                              const float* __restrict__ b2,
                                              const int* __restrict__ gid,
                                              float* __restrict__ out) {
  const int g = blockIdx.x;
  __shared__ int s_lo, s_hi;
  if (threadIdx.x == 0) {
    int a = 0, b = N_NODES;
    while (a < b) { int m = (a + b) >> 1; if (gid[m] < g) a = m + 1; else b = m; }
    s_lo = a;
    b = N_NODES;
    while (a < b) { int m = (a + b) >> 1; if (gid[m] < g + 1) a = m + 1; else b = m; }
    s_hi = a;
  }
  __syncthreads();
  const int lo = s_lo, hi = s_hi, cnt = hi - lo;
  const int j = threadIdx.x & 15;   // feature
  const int r = threadIdx.x >> 4;   // 0..15 node stride lane
  float acc = 0.f;
  for (int n = lo + r; n < hi; n += 16)
    acc += agg2[(size_t)n * 16 + j] * norm_in[n];

  __shared__ float red[256];
  red[threadIdx.x] = acc;
  __syncthreads();
  #pragma unroll
  for (int s = 8; s > 0; s >>= 1) {
    if (r < s) red[threadIdx.x] += red[threadIdx.x + s * 16];
    __syncthreads();
  }
  if (r == 0)
    out[g * 16 + j] = (cnt > 0) ? (red[j] / (float)cnt + b2[j]) : 0.0f;
}

extern "C" void kernel_launch(void* const* d_in, const int* in_sizes, int n_in,
                              void* d_out, int out_size, void* d_ws, size_t ws_size,
                              hipStream_t stream) {
  const float* x   = (const float*)d_in[0];
  const float* W1  = (const float*)d_in[1];
  const float* b1  = (const float*)d_in[2];
  const float* W2  = (const float*)d_in[3];
  const float* b2  = (const float*)d_in[4];
  const int*   src = (const int*)d_in[5];
  const int*   dst = (const int*)d_in[6];
  const int*   gid = (const int*)d_in[7];
  float* out = (float*)d_out;

  // workspace layout (floats):
  //   [0, 64N)        agg1   (later reused: h2 = [0,16N), agg2 = [16N,32N))
  //   [64N, 65N)      deg_out -> norm_out
  //   [65N, 66N)      deg_in  -> norm_in
  //   [66N, 130N)     h1
  float* ws      = (float*)d_ws;
  float* agg1    = ws;
  float* h2      = ws;                          // reuse after K5
  float* agg2    = ws + (size_t)16 * N_NODES;   // reuse after K5
  float* norm_o  = ws + (size_t)64 * N_NODES;
  float* norm_i  = norm_o + N_NODES;
  float* h1      = norm_i + N_NODES;

  // zero: agg1 + degs (contiguous prefix)
  size_t zero_floats = (size_t)66 * N_NODES;
  hipMemsetAsync(d_ws, 0, zero_floats * sizeof(float), stream);

  k_degrees <<<(N_EDGES + 255) / 256, 256, 0, stream>>>(src, dst, norm_o, norm_i);
  k_norms   <<<(N_NODES + 255) / 256, 256, 0, stream>>>(norm_o, norm_i);
  k_gemm1   <<<N_NODES / 32, 256, 0, stream>>>(x, W1, norm_o, h1);
  k_scatter1<<<(size_t)N_EDGES * 64 / 256, 256, 0, stream>>>(src, dst, h1, agg1);
  k_finish1 <<<(N_NODES * 64 + 255) / 256, 256, 0, stream>>>(agg1, norm_i, b1, h1);
  // re-zero agg2 region (it aliases old agg1 space)
  hipMemsetAsync(agg2, 0, (size_t)16 * N_NODES * sizeof(float), stream);
  k_gemm2   <<<(N_NODES + 63) / 64, 256, 0, stream>>>(h1, W2, norm_o, h2);
  k_scatter2<<<(size_t)N_EDGES * 16 / 256, 256, 0, stream>>>(src, dst, h2, agg2);
  k_pool    <<<N_GRAPHS, 256, 0, stream>>>(agg2, norm_i, b2, gid, out);
}

// Round 3
// 625.209 us; speedup vs baseline: 2.0205x; 1.3133x over previous
//
#include <hip/hip_runtime.h>

#define N_NODES 100000
#define N_EDGES 1600000
#define N_GRAPHS 128
#define CHUNK 1024
#define NCHUNK ((N_NODES + CHUNK - 1) / CHUNK)   // 98

// ---------------- K1: deg_out (float hist) + in-degree counts (int hist) ----------------
__global__ void k_deg(const int* __restrict__ src, const int* __restrict__ dst,
                      float* __restrict__ deg_out_f, int* __restrict__ cnt) {
  int e = blockIdx.x * blockDim.x + threadIdx.x;
  if (e < N_EDGES) {
    atomicAdd(&deg_out_f[src[e]], 1.0f);
    atomicAdd(&cnt[dst[e]], 1);
  }
}

// ---------------- scan step 1: per-chunk sums ----------------
__global__ __launch_bounds__(256) void k_s1(const int* __restrict__ cnt, int* __restrict__ chunk_sum) {
  __shared__ int red[256];
  int b = blockIdx.x, t = threadIdx.x;
  int base = b * CHUNK + t * 4;
  int s = 0;
  #pragma unroll
  for (int i = 0; i < 4; ++i) { int idx = base + i; if (idx < N_NODES) s += cnt[idx]; }
  red[t] = s;
  __syncthreads();
  for (int off = 128; off > 0; off >>= 1) {
    if (t < off) red[t] += red[t + off];
    __syncthreads();
  }
  if (t == 0) chunk_sum[b] = red[0];
}

// ---------------- scan step 2: exclusive scan of chunk sums (single block) ----------------
__global__ __launch_bounds__(128) void k_s2(const int* __restrict__ chunk_sum,
                                            int* __restrict__ chunk_off,
                                            int* __restrict__ row_ptr) {
  __shared__ int s[128];
  int t = threadIdx.x;
  int v = (t < NCHUNK) ? chunk_sum[t] : 0;
  s[t] = v;
  __syncthreads();
  for (int off = 1; off < 128; off <<= 1) {
    int a = (t >= off) ? s[t - off] : 0;
    __syncthreads();
    s[t] += a;
    __syncthreads();
  }
  chunk_off[t] = s[t] - v;            // exclusive
  if (t == 0) row_ptr[N_NODES] = N_EDGES;
}

// ---------------- scan step 3: per-chunk exclusive scan + offset -> row_ptr ----------------
__global__ __launch_bounds__(256) void k_s3(const int* __restrict__ cnt,
                                            const int* __restrict__ chunk_off,
                                            int* __restrict__ row_ptr) {
  __shared__ int s[256];
  int b = blockIdx.x, t = threadIdx.x;
  int base = b * CHUNK + t * 4;
  int v0 = 0, v1 = 0, v2 = 0, v3 = 0;
  if (base + 0 < N_NODES) v0 = cnt[base + 0];
  if (base + 1 < N_NODES) v1 = cnt[base + 1];
  if (base + 2 < N_NODES) v2 = cnt[base + 2];
  if (base + 3 < N_NODES) v3 = cnt[base + 3];
  int tsum = v0 + v1 + v2 + v3;
  s[t] = tsum;
  __syncthreads();
  for (int off = 1; off < 256; off <<= 1) {
    int a = (t >= off) ? s[t - off] : 0;
    __syncthreads();
    s[t] += a;
    __syncthreads();
  }
  int excl = s[t] - tsum + chunk_off[b];
  if (base + 0 < N_NODES) row_ptr[base + 0] = excl;
  if (base + 1 < N_NODES) row_ptr[base + 1] = excl + v0;
  if (base + 2 < N_NODES) row_ptr[base + 2] = excl + v0 + v1;
  if (base + 3 < N_NODES) row_ptr[base + 3] = excl + v0 + v1 + v2;
}

// ---------------- fill CSR edge list (src sorted by dst) ----------------
__global__ void k_fill(const int* __restrict__ src, const int* __restrict__ dst,
                       const int* __restrict__ row_ptr, int* __restrict__ cnt2,
                       int* __restrict__ edge_src) {
  int e = blockIdx.x * blockDim.x + threadIdx.x;
  if (e < N_EDGES) {
    int d = dst[e];
    int r = atomicAdd(&cnt2[d], 1);
    edge_src[row_ptr[d] + r] = src[e];
  }
}

// ---------------- norms ----------------
__global__ void k_norms(float* __restrict__ deg_out_f, const int* __restrict__ cnt,
                        float* __restrict__ norm_in) {
  int i = blockIdx.x * blockDim.x + threadIdx.x;
  if (i < N_NODES) {
    deg_out_f[i] = rsqrtf(fmaxf(deg_out_f[i], 1.0f));      // becomes norm_out
    norm_in[i]   = rsqrtf(fmaxf((float)cnt[i], 1.0f));
  }
}

// ---------------- gemm1: h1 = (x * norm_out) @ W1   [N,128]x[128,64] ----------------
__global__ __launch_bounds__(256) void k_gemm1(const float* __restrict__ x,
                                               const float* __restrict__ W1,
                                               const float* __restrict__ norm_out,
                                               float* __restrict__ h1) {
  __shared__ float Wt[128 * 64];   // 32 KB
  __shared__ float xt[32 * 128];   // 16 KB
  const int t = threadIdx.x;
  const int row0 = blockIdx.x * 32;

  const float4* W4 = (const float4*)W1;
  float4* Wt4 = (float4*)Wt;
  #pragma unroll
  for (int i = 0; i < 8; ++i) Wt4[t + 256 * i] = W4[t + 256 * i];

  const float4* x4 = (const float4*)(x + (size_t)row0 * 128);
  float4* xt4 = (float4*)xt;
  #pragma unroll
  for (int i = 0; i < 4; ++i) {
    int idx = t + 256 * i;
    int r = idx >> 5;
    float s = norm_out[row0 + r];
    float4 v = x4[idx];
    v.x *= s; v.y *= s; v.z *= s; v.w *= s;
    xt4[idx] = v;
  }
  __syncthreads();

  const int col = t & 63;
  const int ty  = t >> 6;
  float acc[8] = {0.f,0.f,0.f,0.f,0.f,0.f,0.f,0.f};
  for (int k = 0; k < 128; ++k) {
    float wv = Wt[k * 64 + col];
    #pragma unroll
    for (int i = 0; i < 8; ++i)
      acc[i] += xt[(ty * 8 + i) * 128 + k] * wv;
  }
  #pragma unroll
  for (int i = 0; i < 8; ++i)
    h1[(size_t)(row0 + ty * 8 + i) * 64 + col] = acc[i];
}

// ---------------- fused: gather(h1) -> relu(.*norm_in + b1) -> @W2 * norm_out -> h2 ------
// one wave per node; lane = feature (64)
__global__ __launch_bounds__(256) void k_gather_l1(const int* __restrict__ row_ptr,
                                                   const int* __restrict__ edge_src,
                                                   const float* __restrict__ h1,
                                                   const float* __restrict__ norm_in,
                                                   const float* __restrict__ norm_out,
                                                   const float* __restrict__ b1,
                                                   const float* __restrict__ W2,
                                                   float* __restrict__ h2) {
  __shared__ float W2s[64 * 17];   // padded stride 17
  const int t = threadIdx.x;
  for (int i = t; i < 64 * 16; i += 256) W2s[(i >> 4) * 17 + (i & 15)] = W2[i];
  __syncthreads();

  const int w = t >> 6;            // wave id -> node sub-index
  const int l = t & 63;            // lane = feature
  const int n = blockIdx.x * 4 + w;

  const int lo = row_ptr[n], hi = row_ptr[n + 1];
  float acc = 0.f;
  for (int i = lo; i < hi; ++i) {
    int s = edge_src[i];
    acc += h1[(size_t)s * 64 + l];
  }
  float h1r = fmaxf(acc * norm_in[n] + b1[l], 0.0f);

  // dot: out j = sum_k h1r[k] * W2[k][j], split k over 4 groups of 16
  const int j = l & 15, p = l >> 4;
  float partial = 0.f;
  #pragma unroll
  for (int k = 0; k < 16; ++k) {
    int kk = p * 16 + k;
    float v = __shfl(h1r, kk, 64);
    partial += v * W2s[kk * 17 + j];
  }
  partial += __shfl_xor(partial, 16, 64);
  partial += __shfl_xor(partial, 32, 64);
  if (l < 16) h2[(size_t)n * 16 + l] = norm_out[n] * partial;
}

// ---------------- gather layer2: agg2 = norm_in * sum_edges h2[src]  (16 feats) ----------
__global__ __launch_bounds__(256) void k_gather_l2(const int* __restrict__ row_ptr,
                                                   const int* __restrict__ edge_src,
                                                   const float* __restrict__ h2,
                                                   const float* __restrict__ norm_in,
                                                   float* __restrict__ agg2) {
  const int t = threadIdx.x;
  const int w = t >> 6;
  const int l = t & 63;
  const int n = blockIdx.x * 4 + w;
  const int f = l & 15, p = l >> 4;

  const int lo = row_ptr[n], hi = row_ptr[n + 1];
  float acc = 0.f;
  for (int i = lo + p; i < hi; i += 4)
    acc += h2[(size_t)edge_src[i] * 16 + f];
  acc += __shfl_xor(acc, 16, 64);
  acc += __shfl_xor(acc, 32, 64);
  if (l < 16) agg2[(size_t)n * 16 + f] = acc * norm_in[n];
}

// ---------------- per-graph mean pool (gid sorted, no atomics) ----------------
__global__ __launch_bounds__(256) void k_pool(const float* __restrict__ agg2,
                                              const float* __restrict__ b2,
                                              const int* __restrict__ gid,
                                              float* __restrict__ out) {
  const int g = blockIdx.x;
  __shared__ int s_lo, s_hi;
  if (threadIdx.x == 0) {
    int a = 0, b = N_NODES;
    while (a < b) { int m = (a + b) >> 1; if (gid[m] < g) a = m + 1; else b = m; }
    s_lo = a;
    b = N_NODES;
    while (a < b) { int m = (a + b) >> 1; if (gid[m] < g + 1) a = m + 1; else b = m; }
    s_hi = a;
  }
  __syncthreads();
  const int lo = s_lo, hi = s_hi, cnt = hi - lo;
  const int j = threadIdx.x & 15;
  const int r = threadIdx.x >> 4;
  float acc = 0.f;
  for (int n = lo + r; n < hi; n += 16)
    acc += agg2[(size_t)n * 16 + j];

  __shared__ float red[256];
  red[threadIdx.x] = acc;
  __syncthreads();
  #pragma unroll
  for (int s = 8; s > 0; s >>= 1) {
    if (r < s) red[threadIdx.x] += red[threadIdx.x + s * 16];
    __syncthreads();
  }
  if (r == 0)
    out[g * 16 + j] = (cnt > 0) ? (red[j] / (float)cnt + b2[j]) : 0.0f;
}

extern "C" void kernel_launch(void* const* d_in, const int* in_sizes, int n_in,
                              void* d_out, int out_size, void* d_ws, size_t ws_size,
                              hipStream_t stream) {
  const float* x   = (const float*)d_in[0];
  const float* W1  = (const float*)d_in[1];
  const float* b1  = (const float*)d_in[2];
  const float* W2  = (const float*)d_in[3];
  const float* b2  = (const float*)d_in[4];
  const int*   src = (const int*)d_in[5];
  const int*   dst = (const int*)d_in[6];
  const int*   gid = (const int*)d_in[7];
  float* out = (float*)d_out;

  // workspace layout (4-byte words, all offsets multiple of 4 words for 16B alignment)
  const size_t N = N_NODES;
  char* base = (char*)d_ws;
  float* deg_out_f = (float*)base;                         // [N]  -> becomes norm_out
  int*   cnt       = (int*)(base + 4 * (N));               // [N]
  int*   cnt2      = (int*)(base + 4 * (2 * N));           // [N]
  int*   row_ptr   = (int*)(base + 4 * (3 * N));           // [N+4]
  int*   chunk_sum = (int*)(base + 4 * (4 * N + 4));       // [128]
  int*   chunk_off = (int*)(base + 4 * (4 * N + 132));     // [128]
  float* norm_in   = (float*)(base + 4 * (4 * N + 260));   // [N]
  int*   edge_src  = (int*)(base + 4 * (5 * N + 260));     // [E = 16N]
  float* h1        = (float*)(base + 4 * (21 * N + 260));  // [64N]
  float* h2        = (float*)(base + 4 * (85 * N + 260));  // [16N]
  float* agg2      = (float*)(base + 4 * (101 * N + 260)); // [16N]
  float* norm_out  = deg_out_f;

  // zero: deg_out_f + cnt + cnt2 (contiguous prefix, 3N words = 1.2 MB)
  hipMemsetAsync(d_ws, 0, 3 * N * sizeof(float), stream);

  k_deg      <<<(N_EDGES + 255) / 256, 256, 0, stream>>>(src, dst, deg_out_f, cnt);
  k_s1       <<<NCHUNK, 256, 0, stream>>>(cnt, chunk_sum);
  k_s2       <<<1, 128, 0, stream>>>(chunk_sum, chunk_off, row_ptr);
  k_s3       <<<NCHUNK, 256, 0, stream>>>(cnt, chunk_off, row_ptr);
  k_fill     <<<(N_EDGES + 255) / 256, 256, 0, stream>>>(src, dst, row_ptr, cnt2, edge_src);
  k_norms    <<<(N_NODES + 255) / 256, 256, 0, stream>>>(deg_out_f, cnt, norm_in);
  k_gemm1    <<<N_NODES / 32, 256, 0, stream>>>(x, W1, norm_out, h1);
  k_gather_l1<<<N_NODES / 4, 256, 0, stream>>>(row_ptr, edge_src, h1, norm_in, norm_out, b1, W2, h2);
  k_gather_l2<<<N_NODES / 4, 256, 0, stream>>>(row_ptr, edge_src, h2, norm_in, agg2);
  k_pool     <<<N_GRAPHS, 256, 0, stream>>>(agg2, b2, gid, out);
}

// Round 4
// 531.207 us; speedup vs baseline: 2.3781x; 1.1770x over previous
//
#include <hip/hip_runtime.h>
#include <hip/hip_fp16.h>

#define N_NODES 100000
#define N_EDGES 1600000
#define N_GRAPHS 128
#define CHUNK 1024
#define NCHUNK ((N_NODES + CHUNK - 1) / CHUNK)   // 98

// ---------------- K1: deg_out (float hist) + in-degree counts (int hist) ----------------
__global__ void k_deg(const int* __restrict__ src, const int* __restrict__ dst,
                      float* __restrict__ deg_out_f, int* __restrict__ cnt) {
  int e = blockIdx.x * blockDim.x + threadIdx.x;
  if (e < N_EDGES) {
    atomicAdd(&deg_out_f[src[e]], 1.0f);
    atomicAdd(&cnt[dst[e]], 1);
  }
}

// ---------------- scan step 1: per-chunk sums ----------------
__global__ __launch_bounds__(256) void k_s1(const int* __restrict__ cnt, int* __restrict__ chunk_sum) {
  __shared__ int red[256];
  int b = blockIdx.x, t = threadIdx.x;
  int base = b * CHUNK + t * 4;
  int s = 0;
  #pragma unroll
  for (int i = 0; i < 4; ++i) { int idx = base + i; if (idx < N_NODES) s += cnt[idx]; }
  red[t] = s;
  __syncthreads();
  for (int off = 128; off > 0; off >>= 1) {
    if (t < off) red[t] += red[t + off];
    __syncthreads();
  }
  if (t == 0) chunk_sum[b] = red[0];
}

// ---------------- scan step 2: exclusive scan of chunk sums (single block) ----------------
__global__ __launch_bounds__(128) void k_s2(const int* __restrict__ chunk_sum,
                                            int* __restrict__ chunk_off,
                                            int* __restrict__ row_ptr) {
  __shared__ int s[128];
  int t = threadIdx.x;
  int v = (t < NCHUNK) ? chunk_sum[t] : 0;
  s[t] = v;
  __syncthreads();
  for (int off = 1; off < 128; off <<= 1) {
    int a = (t >= off) ? s[t - off] : 0;
    __syncthreads();
    s[t] += a;
    __syncthreads();
  }
  chunk_off[t] = s[t] - v;            // exclusive
  if (t == 0) row_ptr[N_NODES] = N_EDGES;
}

// ---------------- scan step 3: per-chunk exclusive scan + offset -> row_ptr ----------------
__global__ __launch_bounds__(256) void k_s3(const int* __restrict__ cnt,
                                            const int* __restrict__ chunk_off,
                                            int* __restrict__ row_ptr) {
  __shared__ int s[256];
  int b = blockIdx.x, t = threadIdx.x;
  int base = b * CHUNK + t * 4;
  int v0 = 0, v1 = 0, v2 = 0, v3 = 0;
  if (base + 0 < N_NODES) v0 = cnt[base + 0];
  if (base + 1 < N_NODES) v1 = cnt[base + 1];
  if (base + 2 < N_NODES) v2 = cnt[base + 2];
  if (base + 3 < N_NODES) v3 = cnt[base + 3];
  int tsum = v0 + v1 + v2 + v3;
  s[t] = tsum;
  __syncthreads();
  for (int off = 1; off < 256; off <<= 1) {
    int a = (t >= off) ? s[t - off] : 0;
    __syncthreads();
    s[t] += a;
    __syncthreads();
  }
  int excl = s[t] - tsum + chunk_off[b];
  if (base + 0 < N_NODES) row_ptr[base + 0] = excl;
  if (base + 1 < N_NODES) row_ptr[base + 1] = excl + v0;
  if (base + 2 < N_NODES) row_ptr[base + 2] = excl + v0 + v1;
  if (base + 3 < N_NODES) row_ptr[base + 3] = excl + v0 + v1 + v2;
}

// ---------------- fill CSR edge list (src sorted by dst) ----------------
__global__ void k_fill(const int* __restrict__ src, const int* __restrict__ dst,
                       const int* __restrict__ row_ptr, int* __restrict__ cnt2,
                       int* __restrict__ edge_src) {
  int e = blockIdx.x * blockDim.x + threadIdx.x;
  if (e < N_EDGES) {
    int d = dst[e];
    int r = atomicAdd(&cnt2[d], 1);
    edge_src[row_ptr[d] + r] = src[e];
  }
}

// ---------------- norms ----------------
__global__ void k_norms(float* __restrict__ deg_out_f, const int* __restrict__ cnt,
                        float* __restrict__ norm_in) {
  int i = blockIdx.x * blockDim.x + threadIdx.x;
  if (i < N_NODES) {
    deg_out_f[i] = rsqrtf(fmaxf(deg_out_f[i], 1.0f));      // becomes norm_out
    norm_in[i]   = rsqrtf(fmaxf((float)cnt[i], 1.0f));
  }
}

// ---------------- gemm1: h1 = (x * norm_out) @ W1 -> fp16   [N,128]x[128,64] ----------------
__global__ __launch_bounds__(256) void k_gemm1(const float* __restrict__ x,
                                               const float* __restrict__ W1,
                                               const float* __restrict__ norm_out,
                                               __half* __restrict__ h1h) {
  __shared__ float Wt[128 * 64];   // 32 KB
  __shared__ float xt[32 * 128];   // 16 KB
  const int t = threadIdx.x;
  const int row0 = blockIdx.x * 32;

  const float4* W4 = (const float4*)W1;
  float4* Wt4 = (float4*)Wt;
  #pragma unroll
  for (int i = 0; i < 8; ++i) Wt4[t + 256 * i] = W4[t + 256 * i];

  const float4* x4 = (const float4*)(x + (size_t)row0 * 128);
  float4* xt4 = (float4*)xt;
  #pragma unroll
  for (int i = 0; i < 4; ++i) {
    int idx = t + 256 * i;
    int r = idx >> 5;
    float s = norm_out[row0 + r];
    float4 v = x4[idx];
    v.x *= s; v.y *= s; v.z *= s; v.w *= s;
    xt4[idx] = v;
  }
  __syncthreads();

  const int col = t & 63;
  const int ty  = t >> 6;
  float acc[8] = {0.f,0.f,0.f,0.f,0.f,0.f,0.f,0.f};
  for (int k = 0; k < 128; ++k) {
    float wv = Wt[k * 64 + col];
    #pragma unroll
    for (int i = 0; i < 8; ++i)
      acc[i] += xt[(ty * 8 + i) * 128 + k] * wv;
  }
  #pragma unroll
  for (int i = 0; i < 8; ++i)
    h1h[(size_t)(row0 + ty * 8 + i) * 64 + col] = __float2half(acc[i]);
}

// ---------------- fused: gather(h1) -> relu(.*norm_in + b1) -> @W2 * norm_out -> h2(fp16) --
// one wave per node; lane = feature (64)
__global__ __launch_bounds__(256) void k_gather_l1(const int* __restrict__ row_ptr,
                                                   const int* __restrict__ edge_src,
                                                   const __half* __restrict__ h1h,
                                                   const float* __restrict__ norm_in,
                                                   const float* __restrict__ norm_out,
                                                   const float* __restrict__ b1,
                                                   const float* __restrict__ W2,
                                                   __half* __restrict__ h2h) {
  __shared__ float W2s[64 * 17];   // padded stride 17
  const int t = threadIdx.x;
  for (int i = t; i < 64 * 16; i += 256) W2s[(i >> 4) * 17 + (i & 15)] = W2[i];
  __syncthreads();

  const int w = t >> 6;            // wave id -> node sub-index
  const int l = t & 63;            // lane = feature
  const int n = blockIdx.x * 4 + w;

  const int lo = row_ptr[n], hi = row_ptr[n + 1];
  float a0 = 0.f, a1 = 0.f, a2 = 0.f, a3 = 0.f;
  int i = lo;
  for (; i + 4 <= hi; i += 4) {
    int s0 = edge_src[i + 0], s1 = edge_src[i + 1];
    int s2 = edge_src[i + 2], s3 = edge_src[i + 3];
    a0 += __half2float(h1h[(size_t)s0 * 64 + l]);
    a1 += __half2float(h1h[(size_t)s1 * 64 + l]);
    a2 += __half2float(h1h[(size_t)s2 * 64 + l]);
    a3 += __half2float(h1h[(size_t)s3 * 64 + l]);
  }
  for (; i < hi; ++i)
    a0 += __half2float(h1h[(size_t)edge_src[i] * 64 + l]);
  float acc = (a0 + a1) + (a2 + a3);

  float h1r = fmaxf(acc * norm_in[n] + b1[l], 0.0f);

  // dot: out j = sum_k h1r[k] * W2[k][j], split k over 4 groups of 16
  const int j = l & 15, p = l >> 4;
  float partial = 0.f;
  #pragma unroll
  for (int k = 0; k < 16; ++k) {
    int kk = p * 16 + k;
    float v = __shfl(h1r, kk, 64);
    partial += v * W2s[kk * 17 + j];
  }
  partial += __shfl_xor(partial, 16, 64);
  partial += __shfl_xor(partial, 32, 64);
  if (l < 16) h2h[(size_t)n * 16 + l] = __float2half(norm_out[n] * partial);
}

// ---------------- gather layer2: agg2 = norm_in * sum_edges h2[src]  (16 feats) ----------
__global__ __launch_bounds__(256) void k_gather_l2(const int* __restrict__ row_ptr,
                                                   const int* __restrict__ edge_src,
                                                   const __half* __restrict__ h2h,
                                                   const float* __restrict__ norm_in,
                                                   float* __restrict__ agg2) {
  const int t = threadIdx.x;
  const int w = t >> 6;
  const int l = t & 63;
  const int n = blockIdx.x * 4 + w;
  const int f = l & 15, p = l >> 4;

  const int lo = row_ptr[n], hi = row_ptr[n + 1];
  float a0 = 0.f, a1 = 0.f;
  int i = lo + p;
  for (; i + 4 < hi; i += 8) {
    a0 += __half2float(h2h[(size_t)edge_src[i] * 16 + f]);
    a1 += __half2float(h2h[(size_t)edge_src[i + 4] * 16 + f]);
  }
  if (i < hi) a0 += __half2float(h2h[(size_t)edge_src[i] * 16 + f]);
  float acc = a0 + a1;
  acc += __shfl_xor(acc, 16, 64);
  acc += __shfl_xor(acc, 32, 64);
  if (l < 16) agg2[(size_t)n * 16 + f] = acc * norm_in[n];
}

// ---------------- per-graph mean pool (gid sorted, no atomics) ----------------
__global__ __launch_bounds__(256) void k_pool(const float* __restrict__ agg2,
                                              const float* __restrict__ b2,
                                              const int* __restrict__ gid,
                                              float* __restrict__ out) {
  const int g = blockIdx.x;
  __shared__ int s_lo, s_hi;
  if (threadIdx.x == 0) {
    int a = 0, b = N_NODES;
    while (a < b) { int m = (a + b) >> 1; if (gid[m] < g) a = m + 1; else b = m; }
    s_lo = a;
    b = N_NODES;
    while (a < b) { int m = (a + b) >> 1; if (gid[m] < g + 1) a = m + 1; else b = m; }
    s_hi = a;
  }
  __syncthreads();
  const int lo = s_lo, hi = s_hi, cnt = hi - lo;
  const int j = threadIdx.x & 15;
  const int r = threadIdx.x >> 4;
  float acc = 0.f;
  for (int n = lo + r; n < hi; n += 16)
    acc += agg2[(size_t)n * 16 + j];

  __shared__ float red[256];
  red[threadIdx.x] = acc;
  __syncthreads();
  #pragma unroll
  for (int s = 8; s > 0; s >>= 1) {
    if (r < s) red[threadIdx.x] += red[threadIdx.x + s * 16];
    __syncthreads();
  }
  if (r == 0)
    out[g * 16 + j] = (cnt > 0) ? (red[j] / (float)cnt + b2[j]) : 0.0f;
}

extern "C" void kernel_launch(void* const* d_in, const int* in_sizes, int n_in,
                              void* d_out, int out_size, void* d_ws, size_t ws_size,
                              hipStream_t stream) {
  const float* x   = (const float*)d_in[0];
  const float* W1  = (const float*)d_in[1];
  const float* b1  = (const float*)d_in[2];
  const float* W2  = (const float*)d_in[3];
  const float* b2  = (const float*)d_in[4];
  const int*   src = (const int*)d_in[5];
  const int*   dst = (const int*)d_in[6];
  const int*   gid = (const int*)d_in[7];
  float* out = (float*)d_out;

  // workspace layout (word offsets; all buffers 16B-aligned)
  const size_t N = N_NODES;
  char* base = (char*)d_ws;
  float*  deg_out_f = (float*)base;                         // [N] -> becomes norm_out
  int*    cnt       = (int*)(base + 4 * (N));               // [N]
  int*    cnt2      = (int*)(base + 4 * (2 * N));           // [N]
  int*    row_ptr   = (int*)(base + 4 * (3 * N));           // [N+4]
  int*    chunk_sum = (int*)(base + 4 * (4 * N + 4));       // [128]
  int*    chunk_off = (int*)(base + 4 * (4 * N + 132));     // [128]
  float*  norm_in   = (float*)(base + 4 * (4 * N + 260));   // [N]
  int*    edge_src  = (int*)(base + 4 * (5 * N + 260));     // [E = 16N]
  __half* h1h       = (__half*)(base + 4 * (21 * N + 260)); // [64N halves = 32N words]
  __half* h2h       = (__half*)(base + 4 * (53 * N + 260)); // [16N halves = 8N words]
  float*  agg2      = (float*)(base + 4 * (61 * N + 260));  // [16N]
  float*  norm_out  = deg_out_f;

  // zero: deg_out_f + cnt + cnt2 (contiguous prefix, 3N words = 1.2 MB)
  hipMemsetAsync(d_ws, 0, 3 * N * sizeof(float), stream);

  k_deg      <<<(N_EDGES + 255) / 256, 256, 0, stream>>>(src, dst, deg_out_f, cnt);
  k_s1       <<<NCHUNK, 256, 0, stream>>>(cnt, chunk_sum);
  k_s2       <<<1, 128, 0, stream>>>(chunk_sum, chunk_off, row_ptr);
  k_s3       <<<NCHUNK, 256, 0, stream>>>(cnt, chunk_off, row_ptr);
  k_fill     <<<(N_EDGES + 255) / 256, 256, 0, stream>>>(src, dst, row_ptr, cnt2, edge_src);
  k_norms    <<<(N_NODES + 255) / 256, 256, 0, stream>>>(deg_out_f, cnt, norm_in);
  k_gemm1    <<<N_NODES / 32, 256, 0, stream>>>(x, W1, norm_out, h1h);
  k_gather_l1<<<N_NODES / 4, 256, 0, stream>>>(row_ptr, edge_src, h1h, norm_in, norm_out, b1, W2, h2h);
  k_gather_l2<<<N_NODES / 4, 256, 0, stream>>>(row_ptr, edge_src, h2h, norm_in, agg2);
  k_pool     <<<N_GRAPHS, 256, 0, stream>>>(agg2, b2, gid, out);
}

// Round 5
// 344.965 us; speedup vs baseline: 3.6620x; 1.5399x over previous
//
#include <hip/hip_runtime.h>
#include <hip/hip_fp16.h>

#define N_NODES 100000
#define N_EDGES 1600000
#define N_GRAPHS 128
#define NBUCK 391          // ceil(100000/256) buckets of 256 nodes
#define NBLK 256           // blocks for count/scatter passes
#define CHUNK_E (N_EDGES / NBLK)   // 6250 edges per block

typedef unsigned long long u64;
typedef unsigned int u32;

// ---------------- pass 1: per-(bucket,block) counts of dst and src ----------------
__global__ __launch_bounds__(256) void k_cnt(const int* __restrict__ src,
                                             const int* __restrict__ dst,
                                             int* __restrict__ counts_d,
                                             int* __restrict__ counts_s) {
  __shared__ int hd[NBUCK], hs[NBUCK];
  const int t = threadIdx.x, blk = blockIdx.x;
  for (int j = t; j < NBUCK; j += 256) { hd[j] = 0; hs[j] = 0; }
  __syncthreads();
  const int start = blk * CHUNK_E, end = start + CHUNK_E;
  for (int i = start + t; i < end; i += 256) {
    atomicAdd(&hd[dst[i] >> 8], 1);
    atomicAdd(&hs[src[i] >> 8], 1);
  }
  __syncthreads();
  for (int j = t; j < NBUCK; j += 256) {
    counts_d[j * NBLK + blk] = hd[j];
    counts_s[j * NBLK + blk] = hs[j];
  }
}

// ---------------- pass 2a: per-bucket exclusive scan over blocks ----------------
__global__ __launch_bounds__(256) void k_scanA(int* __restrict__ counts_d,
                                               int* __restrict__ counts_s,
                                               int* __restrict__ totals_d,
                                               int* __restrict__ totals_s) {
  __shared__ int s[256];
  const int b = blockIdx.x, t = threadIdx.x;
  // dst
  int v = counts_d[b * NBLK + t];
  s[t] = v;
  __syncthreads();
  for (int off = 1; off < 256; off <<= 1) {
    int a = (t >= off) ? s[t - off] : 0;
    __syncthreads(); s[t] += a; __syncthreads();
  }
  counts_d[b * NBLK + t] = s[t] - v;          // exclusive over blocks
  if (t == 255) totals_d[b] = s[t];
  __syncthreads();
  // src
  v = counts_s[b * NBLK + t];
  s[t] = v;
  __syncthreads();
  for (int off = 1; off < 256; off <<= 1) {
    int a = (t >= off) ? s[t - off] : 0;
    __syncthreads(); s[t] += a; __syncthreads();
  }
  counts_s[b * NBLK + t] = s[t] - v;
  if (t == 255) totals_s[b] = s[t];
}

// ---------------- pass 2b: exclusive scan over buckets ----------------
__global__ __launch_bounds__(512) void k_scanB(const int* __restrict__ totals_d,
                                               const int* __restrict__ totals_s,
                                               int* __restrict__ boff_d,
                                               int* __restrict__ boff_s,
                                               int* __restrict__ row_ptr) {
  __shared__ int s[512];
  const int t = threadIdx.x;
  int v = (t < NBUCK) ? totals_d[t] : 0;
  s[t] = v;
  __syncthreads();
  for (int off = 1; off < 512; off <<= 1) {
    int a = (t >= off) ? s[t - off] : 0;
    __syncthreads(); s[t] += a; __syncthreads();
  }
  if (t < NBUCK) boff_d[t] = s[t] - v;
  if (t == 0) { boff_d[NBUCK] = N_EDGES; row_ptr[N_NODES] = N_EDGES; }
  __syncthreads();
  v = (t < NBUCK) ? totals_s[t] : 0;
  s[t] = v;
  __syncthreads();
  for (int off = 1; off < 512; off <<= 1) {
    int a = (t >= off) ? s[t - off] : 0;
    __syncthreads(); s[t] += a; __syncthreads();
  }
  if (t < NBUCK) boff_s[t] = s[t] - v;
  if (t == 0) boff_s[NBUCK] = N_EDGES;
}

// ---------------- pass 3: bucket-scatter (dst,src) pairs and src keys ----------------
__global__ __launch_bounds__(256) void k_scatter(const int* __restrict__ src,
                                                 const int* __restrict__ dst,
                                                 const int* __restrict__ counts_d,
                                                 const int* __restrict__ counts_s,
                                                 const int* __restrict__ boff_d,
                                                 const int* __restrict__ boff_s,
                                                 u64* __restrict__ ed,
                                                 int* __restrict__ ssk) {
  __shared__ int cur_d[NBUCK], cur_s[NBUCK];
  const int t = threadIdx.x, blk = blockIdx.x;
  for (int j = t; j < NBUCK; j += 256) {
    cur_d[j] = boff_d[j] + counts_d[j * NBLK + blk];
    cur_s[j] = boff_s[j] + counts_s[j * NBLK + blk];
  }
  __syncthreads();
  const int start = blk * CHUNK_E, end = start + CHUNK_E;
  for (int i = start + t; i < end; i += 256) {
    int d = dst[i], s = src[i];
    int pd = atomicAdd(&cur_d[d >> 8], 1);
    ed[pd] = ((u64)(u32)d << 32) | (u32)s;
    int ps = atomicAdd(&cur_s[s >> 8], 1);
    ssk[ps] = s;
  }
}

// ---------------- pass 4: per-bucket CSR finalize (row_ptr, norm_in, edge_src) ------
__global__ __launch_bounds__(256) void k_bucket_csr(const u64* __restrict__ ed,
                                                    const int* __restrict__ boff_d,
                                                    int* __restrict__ row_ptr,
                                                    float* __restrict__ norm_in,
                                                    int* __restrict__ edge_src) {
  __shared__ int hist[256], scanbuf[256], cursor[256];
  const int b = blockIdx.x, t = threadIdx.x;
  const int base = b << 8;
  const int lo = boff_d[b], hi = boff_d[b + 1];
  hist[t] = 0;
  __syncthreads();
  for (int i = lo + t; i < hi; i += 256) {
    int dl = (int)(ed[i] >> 32) - base;
    atomicAdd(&hist[dl], 1);
  }
  __syncthreads();
  int v = hist[t];
  scanbuf[t] = v;
  __syncthreads();
  for (int off = 1; off < 256; off <<= 1) {
    int a = (t >= off) ? scanbuf[t - off] : 0;
    __syncthreads(); scanbuf[t] += a; __syncthreads();
  }
  int excl = scanbuf[t] - v;
  int node = base + t;
  if (node < N_NODES) {
    row_ptr[node] = lo + excl;
    norm_in[node] = rsqrtf(fmaxf((float)v, 1.0f));
  }
  cursor[t] = excl;
  __syncthreads();
  for (int i = lo + t; i < hi; i += 256) {
    u64 e = ed[i];
    int dl = (int)(e >> 32) - base;
    int p = atomicAdd(&cursor[dl], 1);
    edge_src[lo + p] = (int)(u32)e;
  }
}

// ---------------- pass 5: out-degree from bucket-sorted src keys ----------------
__global__ __launch_bounds__(256) void k_outdeg(const int* __restrict__ ssk,
                                                const int* __restrict__ boff_s,
                                                float* __restrict__ norm_out) {
  __shared__ int hist[256];
  const int b = blockIdx.x, t = threadIdx.x;
  const int base = b << 8;
  const int lo = boff_s[b], hi = boff_s[b + 1];
  hist[t] = 0;
  __syncthreads();
  for (int i = lo + t; i < hi; i += 256)
    atomicAdd(&hist[ssk[i] - base], 1);
  __syncthreads();
  int node = base + t;
  if (node < N_NODES)
    norm_out[node] = rsqrtf(fmaxf((float)hist[t], 1.0f));
}

// ---------------- gemm1: h1 = (x * norm_out) @ W1 -> fp16   [N,128]x[128,64] ----------
__global__ __launch_bounds__(256) void k_gemm1(const float* __restrict__ x,
                                               const float* __restrict__ W1,
                                               const float* __restrict__ norm_out,
                                               __half* __restrict__ h1h) {
  __shared__ float Wt[128 * 64];   // 32 KB
  __shared__ float xt[32 * 128];   // 16 KB
  const int t = threadIdx.x;
  const int row0 = blockIdx.x * 32;

  const float4* W4 = (const float4*)W1;
  float4* Wt4 = (float4*)Wt;
  #pragma unroll
  for (int i = 0; i < 8; ++i) Wt4[t + 256 * i] = W4[t + 256 * i];

  const float4* x4 = (const float4*)(x + (size_t)row0 * 128);
  float4* xt4 = (float4*)xt;
  #pragma unroll
  for (int i = 0; i < 4; ++i) {
    int idx = t + 256 * i;
    int r = idx >> 5;
    float s = norm_out[row0 + r];
    float4 v = x4[idx];
    v.x *= s; v.y *= s; v.z *= s; v.w *= s;
    xt4[idx] = v;
  }
  __syncthreads();

  const int col = t & 63;
  const int ty  = t >> 6;
  float acc[8] = {0.f,0.f,0.f,0.f,0.f,0.f,0.f,0.f};
  for (int k = 0; k < 128; ++k) {
    float wv = Wt[k * 64 + col];
    #pragma unroll
    for (int i = 0; i < 8; ++i)
      acc[i] += xt[(ty * 8 + i) * 128 + k] * wv;
  }
  #pragma unroll
  for (int i = 0; i < 8; ++i)
    h1h[(size_t)(row0 + ty * 8 + i) * 64 + col] = __float2half(acc[i]);
}

// ---------------- fused: gather(h1) -> relu(.*norm_in + b1) -> @W2 * norm_out -> h2 ----
__global__ __launch_bounds__(256) void k_gather_l1(const int* __restrict__ row_ptr,
                                                   const int* __restrict__ edge_src,
                                                   const __half* __restrict__ h1h,
                                                   const float* __restrict__ norm_in,
                                                   const float* __restrict__ norm_out,
                                                   const float* __restrict__ b1,
                                                   const float* __restrict__ W2,
                                                   __half* __restrict__ h2h) {
  __shared__ float W2s[64 * 17];   // padded stride 17
  const int t = threadIdx.x;
  for (int i = t; i < 64 * 16; i += 256) W2s[(i >> 4) * 17 + (i & 15)] = W2[i];
  __syncthreads();

  const int w = t >> 6;            // wave id -> node sub-index
  const int l = t & 63;            // lane = feature
  const int n = blockIdx.x * 4 + w;

  const int lo = row_ptr[n], hi = row_ptr[n + 1];
  float a0 = 0.f, a1 = 0.f, a2 = 0.f, a3 = 0.f;
  int i = lo;
  for (; i + 4 <= hi; i += 4) {
    int s0 = edge_src[i + 0], s1 = edge_src[i + 1];
    int s2 = edge_src[i + 2], s3 = edge_src[i + 3];
    a0 += __half2float(h1h[(size_t)s0 * 64 + l]);
    a1 += __half2float(h1h[(size_t)s1 * 64 + l]);
    a2 += __half2float(h1h[(size_t)s2 * 64 + l]);
    a3 += __half2float(h1h[(size_t)s3 * 64 + l]);
  }
  for (; i < hi; ++i)
    a0 += __half2float(h1h[(size_t)edge_src[i] * 64 + l]);
  float acc = (a0 + a1) + (a2 + a3);

  float h1r = fmaxf(acc * norm_in[n] + b1[l], 0.0f);

  const int j = l & 15, p = l >> 4;
  float partial = 0.f;
  #pragma unroll
  for (int k = 0; k < 16; ++k) {
    int kk = p * 16 + k;
    float v = __shfl(h1r, kk, 64);
    partial += v * W2s[kk * 17 + j];
  }
  partial += __shfl_xor(partial, 16, 64);
  partial += __shfl_xor(partial, 32, 64);
  if (l < 16) h2h[(size_t)n * 16 + l] = __float2half(norm_out[n] * partial);
}

// ---------------- gather layer2: agg2 = norm_in * sum_edges h2[src]  (16 feats) --------
__global__ __launch_bounds__(256) void k_gather_l2(const int* __restrict__ row_ptr,
                                                   const int* __restrict__ edge_src,
                                                   const __half* __restrict__ h2h,
                                                   const float* __restrict__ norm_in,
                                                   float* __restrict__ agg2) {
  const int t = threadIdx.x;
  const int w = t >> 6;
  const int l = t & 63;
  const int n = blockIdx.x * 4 + w;
  const int f = l & 15, p = l >> 4;

  const int lo = row_ptr[n], hi = row_ptr[n + 1];
  float a0 = 0.f, a1 = 0.f;
  int i = lo + p;
  for (; i + 4 < hi; i += 8) {
    a0 += __half2float(h2h[(size_t)edge_src[i] * 16 + f]);
    a1 += __half2float(h2h[(size_t)edge_src[i + 4] * 16 + f]);
  }
  if (i < hi) a0 += __half2float(h2h[(size_t)edge_src[i] * 16 + f]);
  float acc = a0 + a1;
  acc += __shfl_xor(acc, 16, 64);
  acc += __shfl_xor(acc, 32, 64);
  if (l < 16) agg2[(size_t)n * 16 + f] = acc * norm_in[n];
}

// ---------------- per-graph mean pool (gid sorted, no atomics) ----------------
__global__ __launch_bounds__(256) void k_pool(const float* __restrict__ agg2,
                                              const float* __restrict__ b2,
                                              const int* __restrict__ gid,
                                              float* __restrict__ out) {
  const int g = blockIdx.x;
  __shared__ int s_lo, s_hi;
  if (threadIdx.x == 0) {
    int a = 0, b = N_NODES;
    while (a < b) { int m = (a + b) >> 1; if (gid[m] < g) a = m + 1; else b = m; }
    s_lo = a;
    b = N_NODES;
    while (a < b) { int m = (a + b) >> 1; if (gid[m] < g + 1) a = m + 1; else b = m; }
    s_hi = a;
  }
  __syncthreads();
  const int lo = s_lo, hi = s_hi, cnt = hi - lo;
  const int j = threadIdx.x & 15;
  const int r = threadIdx.x >> 4;
  float acc = 0.f;
  for (int n = lo + r; n < hi; n += 16)
    acc += agg2[(size_t)n * 16 + j];

  __shared__ float red[256];
  red[threadIdx.x] = acc;
  __syncthreads();
  #pragma unroll
  for (int s = 8; s > 0; s >>= 1) {
    if (r < s) red[threadIdx.x] += red[threadIdx.x + s * 16];
    __syncthreads();
  }
  if (r == 0)
    out[g * 16 + j] = (cnt > 0) ? (red[j] / (float)cnt + b2[j]) : 0.0f;
}

extern "C" void kernel_launch(void* const* d_in, const int* in_sizes, int n_in,
                              void* d_out, int out_size, void* d_ws, size_t ws_size,
                              hipStream_t stream) {
  const float* x   = (const float*)d_in[0];
  const float* W1  = (const float*)d_in[1];
  const float* b1  = (const float*)d_in[2];
  const float* W2  = (const float*)d_in[3];
  const float* b2  = (const float*)d_in[4];
  const int*   src = (const int*)d_in[5];
  const int*   dst = (const int*)d_in[6];
  const int*   gid = (const int*)d_in[7];
  float* out = (float*)d_out;

  // workspace layout (word offsets). Persistent: norm_out, norm_in, row_ptr, edge_src.
  // Sort scratch (ssk/counts/totals/boffs/ed) is dead after k_outdeg and its space is
  // reused for h1h/h2h/agg2. Total ~7.5M words = 30 MB. Every word is written before
  // read each call -> no memset needed.
  const size_t N = N_NODES, E = N_EDGES;
  float* wsf = (float*)d_ws;
  int*   wsi = (int*)d_ws;

  float* norm_out = wsf;                                  // [N]
  float* norm_in  = wsf + N;                              // [N]
  int*   row_ptr  = wsi + 2 * N;                          // [N+1]
  int*   edge_src = wsi + 3 * N + 16;                     // [E]
  size_t S = 3 * N + 16 + E;                              // scratch base = 1,900,016
  int*   ssk      = wsi + S;                              // [E]
  int*   counts_d = wsi + S + E;                          // [NBUCK*NBLK = 100096]
  int*   counts_s = wsi + S + E + 100096;                 // [100096]
  int*   totals_d = wsi + S + E + 200192;                 // [392]
  int*   totals_s = wsi + S + E + 200584;                 // [392]
  int*   boff_d   = wsi + S + E + 200976;                 // [392]
  int*   boff_s   = wsi + S + E + 201368;                 // [392]
  u64*   ed       = (u64*)(wsi + S + E + 201760);         // [E] u64, offset even -> 8B aligned
  // reuse region (after CSR build):
  __half* h1h     = (__half*)(wsi + S);                   // [64N halves = 32N words]
  __half* h2h     = (__half*)(wsi + S + 32 * N);          // [16N halves = 8N words]
  float*  agg2    = (float*)(wsi + S + 40 * N);           // [16N words]

  k_cnt       <<<NBLK, 256, 0, stream>>>(src, dst, counts_d, counts_s);
  k_scanA     <<<NBUCK, 256, 0, stream>>>(counts_d, counts_s, totals_d, totals_s);
  k_scanB     <<<1, 512, 0, stream>>>(totals_d, totals_s, boff_d, boff_s, row_ptr);
  k_scatter   <<<NBLK, 256, 0, stream>>>(src, dst, counts_d, counts_s, boff_d, boff_s, ed, ssk);
  k_bucket_csr<<<NBUCK, 256, 0, stream>>>(ed, boff_d, row_ptr, norm_in, edge_src);
  k_outdeg    <<<NBUCK, 256, 0, stream>>>(ssk, boff_s, norm_out);
  k_gemm1     <<<N_NODES / 32, 256, 0, stream>>>(x, W1, norm_out, h1h);
  k_gather_l1 <<<N_NODES / 4, 256, 0, stream>>>(row_ptr, edge_src, h1h, norm_in, norm_out, b1, W2, h2h);
  k_gather_l2 <<<N_NODES / 4, 256, 0, stream>>>(row_ptr, edge_src, h2h, norm_in, agg2);
  k_pool      <<<N_GRAPHS, 256, 0, stream>>>(agg2, b2, gid, out);
}

// Round 6
// 321.784 us; speedup vs baseline: 3.9258x; 1.0720x over previous
//
#include <hip/hip_runtime.h>
#include <hip/hip_fp16.h>

#define N_NODES 100000
#define N_EDGES 1600000
#define N_GRAPHS 128
#define NBUCK 391          // ceil(100000/256) buckets of 256 nodes
#define NBLK 256           // blocks for count/scatter passes
#define CHUNK_E (N_EDGES / NBLK)   // 6250 edges per block

typedef unsigned long long u64;
typedef unsigned int u32;

// ---------------- pass 1: per-(bucket,block) counts of dst and src ----------------
__global__ __launch_bounds__(256) void k_cnt(const int* __restrict__ src,
                                             const int* __restrict__ dst,
                                             int* __restrict__ counts_d,
                                             int* __restrict__ counts_s) {
  __shared__ int hd[NBUCK], hs[NBUCK];
  const int t = threadIdx.x, blk = blockIdx.x;
  for (int j = t; j < NBUCK; j += 256) { hd[j] = 0; hs[j] = 0; }
  __syncthreads();
  const int start = blk * CHUNK_E, end = start + CHUNK_E;
  for (int i = start + t; i < end; i += 256) {
    atomicAdd(&hd[dst[i] >> 8], 1);
    atomicAdd(&hs[src[i] >> 8], 1);
  }
  __syncthreads();
  for (int j = t; j < NBUCK; j += 256) {
    counts_d[j * NBLK + blk] = hd[j];
    counts_s[j * NBLK + blk] = hs[j];
  }
}

// ---------------- pass 2a: per-bucket exclusive scan over blocks ----------------
__global__ __launch_bounds__(256) void k_scanA(int* __restrict__ counts_d,
                                               int* __restrict__ counts_s,
                                               int* __restrict__ totals_d,
                                               int* __restrict__ totals_s) {
  __shared__ int s[256];
  const int b = blockIdx.x, t = threadIdx.x;
  int v = counts_d[b * NBLK + t];
  s[t] = v;
  __syncthreads();
  for (int off = 1; off < 256; off <<= 1) {
    int a = (t >= off) ? s[t - off] : 0;
    __syncthreads(); s[t] += a; __syncthreads();
  }
  counts_d[b * NBLK + t] = s[t] - v;          // exclusive over blocks
  if (t == 255) totals_d[b] = s[t];
  __syncthreads();
  v = counts_s[b * NBLK + t];
  s[t] = v;
  __syncthreads();
  for (int off = 1; off < 256; off <<= 1) {
    int a = (t >= off) ? s[t - off] : 0;
    __syncthreads(); s[t] += a; __syncthreads();
  }
  counts_s[b * NBLK + t] = s[t] - v;
  if (t == 255) totals_s[b] = s[t];
}

// ---------------- pass 2b: exclusive scan over buckets ----------------
__global__ __launch_bounds__(512) void k_scanB(const int* __restrict__ totals_d,
                                               const int* __restrict__ totals_s,
                                               int* __restrict__ boff_d,
                                               int* __restrict__ boff_s,
                                               int* __restrict__ row_ptr) {
  __shared__ int s[512];
  const int t = threadIdx.x;
  int v = (t < NBUCK) ? totals_d[t] : 0;
  s[t] = v;
  __syncthreads();
  for (int off = 1; off < 512; off <<= 1) {
    int a = (t >= off) ? s[t - off] : 0;
    __syncthreads(); s[t] += a; __syncthreads();
  }
  if (t < NBUCK) boff_d[t] = s[t] - v;
  if (t == 0) { boff_d[NBUCK] = N_EDGES; row_ptr[N_NODES] = N_EDGES; }
  __syncthreads();
  v = (t < NBUCK) ? totals_s[t] : 0;
  s[t] = v;
  __syncthreads();
  for (int off = 1; off < 512; off <<= 1) {
    int a = (t >= off) ? s[t - off] : 0;
    __syncthreads(); s[t] += a; __syncthreads();
  }
  if (t < NBUCK) boff_s[t] = s[t] - v;
  if (t == 0) boff_s[NBUCK] = N_EDGES;
}

// ---------------- pass 3: bucket-scatter (dst,src) pairs and src keys ----------------
__global__ __launch_bounds__(256) void k_scatter(const int* __restrict__ src,
                                                 const int* __restrict__ dst,
                                                 const int* __restrict__ counts_d,
                                                 const int* __restrict__ counts_s,
                                                 const int* __restrict__ boff_d,
                                                 const int* __restrict__ boff_s,
                                                 u64* __restrict__ ed,
                                                 int* __restrict__ ssk) {
  __shared__ int cur_d[NBUCK], cur_s[NBUCK];
  const int t = threadIdx.x, blk = blockIdx.x;
  for (int j = t; j < NBUCK; j += 256) {
    cur_d[j] = boff_d[j] + counts_d[j * NBLK + blk];
    cur_s[j] = boff_s[j] + counts_s[j * NBLK + blk];
  }
  __syncthreads();
  const int start = blk * CHUNK_E, end = start + CHUNK_E;
  for (int i = start + t; i < end; i += 256) {
    int d = dst[i], s = src[i];
    int pd = atomicAdd(&cur_d[d >> 8], 1);
    ed[pd] = ((u64)(u32)d << 32) | (u32)s;
    int ps = atomicAdd(&cur_s[s >> 8], 1);
    ssk[ps] = s;
  }
}

// ---------------- pass 4: per-bucket CSR finalize (row_ptr, norm_in, edge_src) ------
__global__ __launch_bounds__(256) void k_bucket_csr(const u64* __restrict__ ed,
                                                    const int* __restrict__ boff_d,
                                                    int* __restrict__ row_ptr,
                                                    float* __restrict__ norm_in,
                                                    int* __restrict__ edge_src) {
  __shared__ int hist[256], scanbuf[256], cursor[256];
  const int b = blockIdx.x, t = threadIdx.x;
  const int base = b << 8;
  const int lo = boff_d[b], hi = boff_d[b + 1];
  hist[t] = 0;
  __syncthreads();
  for (int i = lo + t; i < hi; i += 256) {
    int dl = (int)(ed[i] >> 32) - base;
    atomicAdd(&hist[dl], 1);
  }
  __syncthreads();
  int v = hist[t];
  scanbuf[t] = v;
  __syncthreads();
  for (int off = 1; off < 256; off <<= 1) {
    int a = (t >= off) ? scanbuf[t - off] : 0;
    __syncthreads(); scanbuf[t] += a; __syncthreads();
  }
  int excl = scanbuf[t] - v;
  int node = base + t;
  if (node < N_NODES) {
    row_ptr[node] = lo + excl;
    norm_in[node] = rsqrtf(fmaxf((float)v, 1.0f));
  }
  cursor[t] = excl;
  __syncthreads();
  for (int i = lo + t; i < hi; i += 256) {
    u64 e = ed[i];
    int dl = (int)(e >> 32) - base;
    int p = atomicAdd(&cursor[dl], 1);
    edge_src[lo + p] = (int)(u32)e;
  }
}

// ---------------- pass 5: out-degree from bucket-sorted src keys ----------------
__global__ __launch_bounds__(256) void k_outdeg(const int* __restrict__ ssk,
                                                const int* __restrict__ boff_s,
                                                float* __restrict__ norm_out) {
  __shared__ int hist[256];
  const int b = blockIdx.x, t = threadIdx.x;
  const int base = b << 8;
  const int lo = boff_s[b], hi = boff_s[b + 1];
  hist[t] = 0;
  __syncthreads();
  for (int i = lo + t; i < hi; i += 256)
    atomicAdd(&hist[ssk[i] - base], 1);
  __syncthreads();
  int node = base + t;
  if (node < N_NODES)
    norm_out[node] = rsqrtf(fmaxf((float)hist[t], 1.0f));
}

// ---------------- gemm1: h1 = (x * norm_out) @ W1 -> fp16   [N,128]x[128,64] ----------
// 64x64 tile / block, 4x4 register tile / thread, ds_read_b128 both operands.
__global__ __launch_bounds__(256) void k_gemm1(const float* __restrict__ x,
                                               const float* __restrict__ W1,
                                               const float* __restrict__ norm_out,
                                               __half* __restrict__ h1h) {
  __shared__ float Wt[128 * 64];    // [k][col], native layout, 32 KB
  __shared__ float xt[64 * 132];    // [row][k], stride 132 (pad), ~33.8 KB
  const int t = threadIdx.x;
  const int row0 = blockIdx.x * 64;

  // stage W1 (2048 float4)
  const float4* W4 = (const float4*)W1;
  float4* Wt4 = (float4*)Wt;
  #pragma unroll
  for (int i = 0; i < 8; ++i) Wt4[t + 256 * i] = W4[t + 256 * i];

  // stage 64 rows of x (2048 float4), scaled by norm_out, with row guard
  const float4* x4 = (const float4*)x;
  #pragma unroll
  for (int i = 0; i < 8; ++i) {
    int idx = t + 256 * i;           // 0..2047
    int r = idx >> 5;                // 0..63
    int c4 = idx & 31;               // float4 index within row
    int row = row0 + r;
    float4 v = make_float4(0.f, 0.f, 0.f, 0.f);
    if (row < N_NODES) {
      float s = norm_out[row];
      v = x4[(size_t)row * 32 + c4];
      v.x *= s; v.y *= s; v.z *= s; v.w *= s;
    }
    *(float4*)&xt[r * 132 + c4 * 4] = v;
  }
  __syncthreads();

  const int tc = (t & 15) * 4;      // col base
  const int tr = (t >> 4) * 4;      // row base
  float acc[4][4] = {{0.f}};
  for (int k = 0; k < 128; k += 4) {
    float4 xa[4], wb[4];
    #pragma unroll
    for (int i = 0; i < 4; ++i) xa[i] = *(const float4*)&xt[(tr + i) * 132 + k];
    #pragma unroll
    for (int j = 0; j < 4; ++j) wb[j] = *(const float4*)&Wt[(k + j) * 64 + tc];
    #pragma unroll
    for (int i = 0; i < 4; ++i) {
      const float* xp = (const float*)&xa[i];
      #pragma unroll
      for (int j = 0; j < 4; ++j) {
        const float* wp = (const float*)&wb[j];
        acc[i][0] += xp[j] * wp[0];
        acc[i][1] += xp[j] * wp[1];
        acc[i][2] += xp[j] * wp[2];
        acc[i][3] += xp[j] * wp[3];
      }
    }
  }
  #pragma unroll
  for (int i = 0; i < 4; ++i) {
    int row = row0 + tr + i;
    if (row < N_NODES) {
      __half2 p0 = __float22half2_rn(make_float2(acc[i][0], acc[i][1]));
      __half2 p1 = __float22half2_rn(make_float2(acc[i][2], acc[i][3]));
      uint2 pk = make_uint2(*(u32*)&p0, *(u32*)&p1);
      *(uint2*)(h1h + (size_t)row * 64 + tc) = pk;
    }
  }
}

// ---------------- fused: gather(h1) -> relu(.*norm_in + b1) -> @W2 * norm_out -> h2 ----
// one wave per node; 32 lanes per edge (u32 = 2 fp16 feats/lane), 2 edges per load instr
__global__ __launch_bounds__(256) void k_gather_l1(const int* __restrict__ row_ptr,
                                                   const int* __restrict__ edge_src,
                                                   const __half* __restrict__ h1h,
                                                   const float* __restrict__ norm_in,
                                                   const float* __restrict__ norm_out,
                                                   const float* __restrict__ b1,
                                                   const float* __restrict__ W2,
                                                   __half* __restrict__ h2h) {
  __shared__ float W2s[64 * 17];   // padded stride 17
  const int t = threadIdx.x;
  for (int i = t; i < 64 * 16; i += 256) W2s[(i >> 4) * 17 + (i & 15)] = W2[i];
  __syncthreads();

  const int w = t >> 6;            // wave id -> node sub-index
  const int l = t & 63;
  const int n = blockIdx.x * 4 + w;
  const int half = l >> 5;         // which edge of the pair
  const int c = l & 31;            // u32 (feature-pair) index within row

  const u32* __restrict__ h1u = (const u32*)h1h;
  const int lo = row_ptr[n], hi = row_ptr[n + 1];

  float2 a0 = {0.f, 0.f}, a1 = {0.f, 0.f}, a2 = {0.f, 0.f}, a3 = {0.f, 0.f};
  int i = lo;
  for (; i + 8 <= hi; i += 8) {
    int sv = edge_src[i + (l & 7)];          // 8 srcs, broadcast via shfl
    int s0 = __shfl(sv, 0 + half, 64);
    int s1 = __shfl(sv, 2 + half, 64);
    int s2 = __shfl(sv, 4 + half, 64);
    int s3 = __shfl(sv, 6 + half, 64);
    u32 v0 = h1u[(size_t)s0 * 32 + c];
    u32 v1 = h1u[(size_t)s1 * 32 + c];
    u32 v2 = h1u[(size_t)s2 * 32 + c];
    u32 v3 = h1u[(size_t)s3 * 32 + c];
    float2 f0 = __half22float2(*(__half2*)&v0);
    float2 f1 = __half22float2(*(__half2*)&v1);
    float2 f2 = __half22float2(*(__half2*)&v2);
    float2 f3 = __half22float2(*(__half2*)&v3);
    a0.x += f0.x; a0.y += f0.y;
    a1.x += f1.x; a1.y += f1.y;
    a2.x += f2.x; a2.y += f2.y;
    a3.x += f3.x; a3.y += f3.y;
  }
  for (; i + 2 <= hi; i += 2) {
    int s = edge_src[i + half];
    u32 v = h1u[(size_t)s * 32 + c];
    float2 f = __half22float2(*(__half2*)&v);
    a0.x += f.x; a0.y += f.y;
  }
  if (i < hi && half == 0) {
    int s = edge_src[i];
    u32 v = h1u[(size_t)s * 32 + c];
    float2 f = __half22float2(*(__half2*)&v);
    a0.x += f.x; a0.y += f.y;
  }
  float accx = (a0.x + a1.x) + (a2.x + a3.x);
  float accy = (a0.y + a1.y) + (a2.y + a3.y);
  accx += __shfl_xor(accx, 32, 64);          // combine the two half-wave edge sets
  accy += __shfl_xor(accy, 32, 64);

  // lane (either half) holds features (2c, 2c+1)
  const float ni = norm_in[n];
  const float2 bb = ((const float2*)b1)[c];
  float h1x = fmaxf(accx * ni + bb.x, 0.0f);
  float h1y = fmaxf(accy * ni + bb.y, 0.0f);

  // dot: out j = sum_k h1r[k]*W2[k][j]; k split over 4 groups of 16
  const int j = l & 15, p = l >> 4;
  float partial = 0.f;
  #pragma unroll
  for (int kk = 0; kk < 16; kk += 2) {
    int sl = p * 8 + (kk >> 1);              // source lane holding pair k=(p*16+kk)
    float vx = __shfl(h1x, sl, 64);
    float vy = __shfl(h1y, sl, 64);
    partial += vx * W2s[(p * 16 + kk) * 17 + j];
    partial += vy * W2s[(p * 16 + kk + 1) * 17 + j];
  }
  partial += __shfl_xor(partial, 16, 64);
  partial += __shfl_xor(partial, 32, 64);
  if (l < 16) h2h[(size_t)n * 16 + l] = __float2half(norm_out[n] * partial);
}

// ---------------- gather layer2: agg2 = norm_in * sum_edges h2[src]  (16 feats) --------
// 8 lanes per edge (u32 loads), 8 edges per load instr
__global__ __launch_bounds__(256) void k_gather_l2(const int* __restrict__ row_ptr,
                                                   const int* __restrict__ edge_src,
                                                   const __half* __restrict__ h2h,
                                                   const float* __restrict__ norm_in,
                                                   float* __restrict__ agg2) {
  const int t = threadIdx.x;
  const int w = t >> 6;
  const int l = t & 63;
  const int n = blockIdx.x * 4 + w;
  const int f2 = l & 7;            // u32 feature-pair index
  const int p = l >> 3;            // 8 edge slices

  const u32* __restrict__ h2u = (const u32*)h2h;
  const int lo = row_ptr[n], hi = row_ptr[n + 1];

  float ax = 0.f, ay = 0.f, bx = 0.f, by = 0.f;
  int i = lo + p;
  for (; i + 8 < hi; i += 16) {
    int s0 = edge_src[i], s1 = edge_src[i + 8];
    u32 v0 = h2u[(size_t)s0 * 8 + f2];
    u32 v1 = h2u[(size_t)s1 * 8 + f2];
    float2 g0 = __half22float2(*(__half2*)&v0);
    float2 g1 = __half22float2(*(__half2*)&v1);
    ax += g0.x; ay += g0.y;
    bx += g1.x; by += g1.y;
  }
  if (i < hi) {
    int s = edge_src[i];
    u32 v = h2u[(size_t)s * 8 + f2];
    float2 g = __half22float2(*(__half2*)&v);
    ax += g.x; ay += g.y;
  }
  float sx = ax + bx, sy = ay + by;
  sx += __shfl_xor(sx, 8, 64);  sy += __shfl_xor(sy, 8, 64);
  sx += __shfl_xor(sx, 16, 64); sy += __shfl_xor(sy, 16, 64);
  sx += __shfl_xor(sx, 32, 64); sy += __shfl_xor(sy, 32, 64);
  if (l < 8) {
    float ni = norm_in[n];
    ((float2*)agg2)[(size_t)n * 8 + f2] = make_float2(sx * ni, sy * ni);
  }
}

// ---------------- per-graph mean pool (gid sorted, no atomics) ----------------
__global__ __launch_bounds__(256) void k_pool(const float* __restrict__ agg2,
                                              const float* __restrict__ b2,
                                              const int* __restrict__ gid,
                                              float* __restrict__ out) {
  const int g = blockIdx.x;
  __shared__ int s_lo, s_hi;
  if (threadIdx.x == 0) {
    int a = 0, b = N_NODES;
    while (a < b) { int m = (a + b) >> 1; if (gid[m] < g) a = m + 1; else b = m; }
    s_lo = a;
    b = N_NODES;
    while (a < b) { int m = (a + b) >> 1; if (gid[m] < g + 1) a = m + 1; else b = m; }
    s_hi = a;
  }
  __syncthreads();
  const int lo = s_lo, hi = s_hi, cnt = hi - lo;
  const int j = threadIdx.x & 15;
  const int r = threadIdx.x >> 4;
  float acc = 0.f;
  for (int n = lo + r; n < hi; n += 16)
    acc += agg2[(size_t)n * 16 + j];

  __shared__ float red[256];
  red[threadIdx.x] = acc;
  __syncthreads();
  #pragma unroll
  for (int s = 8; s > 0; s >>= 1) {
    if (r < s) red[threadIdx.x] += red[threadIdx.x + s * 16];
    __syncthreads();
  }
  if (r == 0)
    out[g * 16 + j] = (cnt > 0) ? (red[j] / (float)cnt + b2[j]) : 0.0f;
}

extern "C" void kernel_launch(void* const* d_in, const int* in_sizes, int n_in,
                              void* d_out, int out_size, void* d_ws, size_t ws_size,
                              hipStream_t stream) {
  const float* x   = (const float*)d_in[0];
  const float* W1  = (const float*)d_in[1];
  const float* b1  = (const float*)d_in[2];
  const float* W2  = (const float*)d_in[3];
  const float* b2  = (const float*)d_in[4];
  const int*   src = (const int*)d_in[5];
  const int*   dst = (const int*)d_in[6];
  const int*   gid = (const int*)d_in[7];
  float* out = (float*)d_out;

  const size_t N = N_NODES, E = N_EDGES;
  float* wsf = (float*)d_ws;
  int*   wsi = (int*)d_ws;

  float* norm_out = wsf;                                  // [N]
  float* norm_in  = wsf + N;                              // [N]
  int*   row_ptr  = wsi + 2 * N;                          // [N+1]
  int*   edge_src = wsi + 3 * N + 16;                     // [E]
  size_t S = 3 * N + 16 + E;                              // scratch base
  int*   ssk      = wsi + S;                              // [E]
  int*   counts_d = wsi + S + E;                          // [NBUCK*NBLK]
  int*   counts_s = wsi + S + E + 100096;                 // [NBUCK*NBLK]
  int*   totals_d = wsi + S + E + 200192;                 // [392]
  int*   totals_s = wsi + S + E + 200584;                 // [392]
  int*   boff_d   = wsi + S + E + 200976;                 // [392]
  int*   boff_s   = wsi + S + E + 201368;                 // [392]
  u64*   ed       = (u64*)(wsi + S + E + 201760);         // [E] u64
  // reuse region (after CSR build):
  __half* h1h     = (__half*)(wsi + S);                   // [64N halves]
  __half* h2h     = (__half*)(wsi + S + 32 * N);          // [16N halves]
  float*  agg2    = (float*)(wsi + S + 40 * N);           // [16N]

  k_cnt       <<<NBLK, 256, 0, stream>>>(src, dst, counts_d, counts_s);
  k_scanA     <<<NBUCK, 256, 0, stream>>>(counts_d, counts_s, totals_d, totals_s);
  k_scanB     <<<1, 512, 0, stream>>>(totals_d, totals_s, boff_d, boff_s, row_ptr);
  k_scatter   <<<NBLK, 256, 0, stream>>>(src, dst, counts_d, counts_s, boff_d, boff_s, ed, ssk);
  k_bucket_csr<<<NBUCK, 256, 0, stream>>>(ed, boff_d, row_ptr, norm_in, edge_src);
  k_outdeg    <<<NBUCK, 256, 0, stream>>>(ssk, boff_s, norm_out);
  k_gemm1     <<<(N_NODES + 63) / 64, 256, 0, stream>>>(x, W1, norm_out, h1h);
  k_gather_l1 <<<N_NODES / 4, 256, 0, stream>>>(row_ptr, edge_src, h1h, norm_in, norm_out, b1, W2, h2h);
  k_gather_l2 <<<N_NODES / 4, 256, 0, stream>>>(row_ptr, edge_src, h2h, norm_in, agg2);
  k_pool      <<<N_GRAPHS, 256, 0, stream>>>(agg2, b2, gid, out);
}

// Round 7
// 308.485 us; speedup vs baseline: 4.0951x; 1.0431x over previous
//
#include <hip/hip_runtime.h>
#include <hip/hip_fp16.h>

#define N_NODES 100000
#define N_EDGES 1600000
#define N_GRAPHS 128
#define NBUCK 391            // ceil(100000/256) buckets of 256 nodes
#define NBLK 250             // blocks for count/scatter passes
#define CHUNK_E4 1600        // int4 elements per block (6400 edges)

typedef unsigned long long u64;
typedef unsigned int u32;
typedef unsigned char u8;

// ---------------- pass 1: per-(bucket,block) counts of dst and src ----------------
__global__ __launch_bounds__(256) void k_cnt(const int4* __restrict__ src4,
                                             const int4* __restrict__ dst4,
                                             int* __restrict__ counts_d,
                                             int* __restrict__ counts_s) {
  __shared__ int hd[NBUCK], hs[NBUCK];
  const int t = threadIdx.x, blk = blockIdx.x;
  for (int j = t; j < NBUCK; j += 256) { hd[j] = 0; hs[j] = 0; }
  __syncthreads();
  const int start = blk * CHUNK_E4, end = start + CHUNK_E4;
  for (int i = start + t; i < end; i += 256) {
    int4 d = dst4[i]; int4 s = src4[i];
    atomicAdd(&hd[d.x >> 8], 1); atomicAdd(&hd[d.y >> 8], 1);
    atomicAdd(&hd[d.z >> 8], 1); atomicAdd(&hd[d.w >> 8], 1);
    atomicAdd(&hs[s.x >> 8], 1); atomicAdd(&hs[s.y >> 8], 1);
    atomicAdd(&hs[s.z >> 8], 1); atomicAdd(&hs[s.w >> 8], 1);
  }
  __syncthreads();
  for (int j = t; j < NBUCK; j += 256) {
    counts_d[j * NBLK + blk] = hd[j];
    counts_s[j * NBLK + blk] = hs[j];
  }
}

// ---------------- pass 2a: per-bucket exclusive scan over blocks ----------------
__global__ __launch_bounds__(256) void k_scanA(int* __restrict__ counts_d,
                                               int* __restrict__ counts_s,
                                               int* __restrict__ totals_d,
                                               int* __restrict__ totals_s) {
  __shared__ int s[256];
  const int b = blockIdx.x, t = threadIdx.x;
  int v = (t < NBLK) ? counts_d[b * NBLK + t] : 0;
  s[t] = v;
  __syncthreads();
  for (int off = 1; off < 256; off <<= 1) {
    int a = (t >= off) ? s[t - off] : 0;
    __syncthreads(); s[t] += a; __syncthreads();
  }
  if (t < NBLK) counts_d[b * NBLK + t] = s[t] - v;
  if (t == 255) totals_d[b] = s[t];
  __syncthreads();
  v = (t < NBLK) ? counts_s[b * NBLK + t] : 0;
  s[t] = v;
  __syncthreads();
  for (int off = 1; off < 256; off <<= 1) {
    int a = (t >= off) ? s[t - off] : 0;
    __syncthreads(); s[t] += a; __syncthreads();
  }
  if (t < NBLK) counts_s[b * NBLK + t] = s[t] - v;
  if (t == 255) totals_s[b] = s[t];
}

// ---------------- pass 2b: exclusive scan over buckets ----------------
__global__ __launch_bounds__(512) void k_scanB(const int* __restrict__ totals_d,
                                               const int* __restrict__ totals_s,
                                               int* __restrict__ boff_d,
                                               int* __restrict__ boff_s,
                                               int* __restrict__ row_ptr) {
  __shared__ int s[512];
  const int t = threadIdx.x;
  int v = (t < NBUCK) ? totals_d[t] : 0;
  s[t] = v;
  __syncthreads();
  for (int off = 1; off < 512; off <<= 1) {
    int a = (t >= off) ? s[t - off] : 0;
    __syncthreads(); s[t] += a; __syncthreads();
  }
  if (t < NBUCK) boff_d[t] = s[t] - v;
  if (t == 0) { boff_d[NBUCK] = N_EDGES; row_ptr[N_NODES] = N_EDGES; }
  __syncthreads();
  v = (t < NBUCK) ? totals_s[t] : 0;
  s[t] = v;
  __syncthreads();
  for (int off = 1; off < 512; off <<= 1) {
    int a = (t >= off) ? s[t - off] : 0;
    __syncthreads(); s[t] += a; __syncthreads();
  }
  if (t < NBUCK) boff_s[t] = s[t] - v;
  if (t == 0) boff_s[NBUCK] = N_EDGES;
}

// ---------------- pass 3: bucket-scatter packed (dl,src) u32 and src low-bytes ------
__global__ __launch_bounds__(256) void k_scatter(const int4* __restrict__ src4,
                                                 const int4* __restrict__ dst4,
                                                 const int* __restrict__ counts_d,
                                                 const int* __restrict__ counts_s,
                                                 const int* __restrict__ boff_d,
                                                 const int* __restrict__ boff_s,
                                                 u32* __restrict__ ed,
                                                 u8* __restrict__ ssk8) {
  __shared__ int cur_d[NBUCK], cur_s[NBUCK];
  const int t = threadIdx.x, blk = blockIdx.x;
  for (int j = t; j < NBUCK; j += 256) {
    cur_d[j] = boff_d[j] + counts_d[j * NBLK + blk];
    cur_s[j] = boff_s[j] + counts_s[j * NBLK + blk];
  }
  __syncthreads();
  const int start = blk * CHUNK_E4, end = start + CHUNK_E4;
  for (int i = start + t; i < end; i += 256) {
    int4 d4 = dst4[i]; int4 s4 = src4[i];
    {
      int d = d4.x, s = s4.x;
      int pd = atomicAdd(&cur_d[d >> 8], 1);
      ed[pd] = ((u32)(d & 255) << 24) | (u32)s;
      int ps = atomicAdd(&cur_s[s >> 8], 1);
      ssk8[ps] = (u8)(s & 255);
    }
    {
      int d = d4.y, s = s4.y;
      int pd = atomicAdd(&cur_d[d >> 8], 1);
      ed[pd] = ((u32)(d & 255) << 24) | (u32)s;
      int ps = atomicAdd(&cur_s[s >> 8], 1);
      ssk8[ps] = (u8)(s & 255);
    }
    {
      int d = d4.z, s = s4.z;
      int pd = atomicAdd(&cur_d[d >> 8], 1);
      ed[pd] = ((u32)(d & 255) << 24) | (u32)s;
      int ps = atomicAdd(&cur_s[s >> 8], 1);
      ssk8[ps] = (u8)(s & 255);
    }
    {
      int d = d4.w, s = s4.w;
      int pd = atomicAdd(&cur_d[d >> 8], 1);
      ed[pd] = ((u32)(d & 255) << 24) | (u32)s;
      int ps = atomicAdd(&cur_s[s >> 8], 1);
      ssk8[ps] = (u8)(s & 255);
    }
  }
}

// ---------------- pass 4: per-bucket CSR finalize (row_ptr, norm_in, edge_src) ------
__global__ __launch_bounds__(256) void k_bucket_csr(const u32* __restrict__ ed,
                                                    const int* __restrict__ boff_d,
                                                    int* __restrict__ row_ptr,
                                                    float* __restrict__ norm_in,
                                                    int* __restrict__ edge_src) {
  __shared__ int hist[256], scanbuf[256], cursor[256];
  const int b = blockIdx.x, t = threadIdx.x;
  const int base = b << 8;
  const int lo = boff_d[b], hi = boff_d[b + 1];
  hist[t] = 0;
  __syncthreads();
  for (int i = lo + t; i < hi; i += 256)
    atomicAdd(&hist[ed[i] >> 24], 1);
  __syncthreads();
  int v = hist[t];
  scanbuf[t] = v;
  __syncthreads();
  for (int off = 1; off < 256; off <<= 1) {
    int a = (t >= off) ? scanbuf[t - off] : 0;
    __syncthreads(); scanbuf[t] += a; __syncthreads();
  }
  int excl = scanbuf[t] - v;
  int node = base + t;
  if (node < N_NODES) {
    row_ptr[node] = lo + excl;
    norm_in[node] = rsqrtf(fmaxf((float)v, 1.0f));
  }
  cursor[t] = excl;
  __syncthreads();
  for (int i = lo + t; i < hi; i += 256) {
    u32 e = ed[i];
    int p = atomicAdd(&cursor[e >> 24], 1);
    edge_src[lo + p] = (int)(e & 0x00FFFFFFu);
  }
}

// ---------------- pass 5: out-degree from bucket-sorted src low-bytes ----------------
__global__ __launch_bounds__(256) void k_outdeg(const u8* __restrict__ ssk8,
                                                const int* __restrict__ boff_s,
                                                float* __restrict__ norm_out) {
  __shared__ int hist[256];
  const int b = blockIdx.x, t = threadIdx.x;
  const int base = b << 8;
  const int lo = boff_s[b], hi = boff_s[b + 1];
  hist[t] = 0;
  __syncthreads();
  for (int i = lo + t; i < hi; i += 256)
    atomicAdd(&hist[ssk8[i]], 1);
  __syncthreads();
  int node = base + t;
  if (node < N_NODES)
    norm_out[node] = rsqrtf(fmaxf((float)hist[t], 1.0f));
}

// ---------------- gemm1: h1 = (x * norm_out) @ W1 -> fp16   [N,128]x[128,64] ----------
__global__ __launch_bounds__(256) void k_gemm1(const float* __restrict__ x,
                                               const float* __restrict__ W1,
                                               const float* __restrict__ norm_out,
                                               __half* __restrict__ h1h) {
  __shared__ float Wt[128 * 64];    // [k][col], native layout
  __shared__ float xt[64 * 132];    // [row][k], stride 132 (pad)
  const int t = threadIdx.x;
  const int row0 = blockIdx.x * 64;

  const float4* W4 = (const float4*)W1;
  float4* Wt4 = (float4*)Wt;
  #pragma unroll
  for (int i = 0; i < 8; ++i) Wt4[t + 256 * i] = W4[t + 256 * i];

  const float4* x4 = (const float4*)x;
  #pragma unroll
  for (int i = 0; i < 8; ++i) {
    int idx = t + 256 * i;           // 0..2047
    int r = idx >> 5;                // 0..63
    int c4 = idx & 31;
    int row = row0 + r;
    float4 v = make_float4(0.f, 0.f, 0.f, 0.f);
    if (row < N_NODES) {
      float s = norm_out[row];
      v = x4[(size_t)row * 32 + c4];
      v.x *= s; v.y *= s; v.z *= s; v.w *= s;
    }
    *(float4*)&xt[r * 132 + c4 * 4] = v;
  }
  __syncthreads();

  const int tc = (t & 15) * 4;
  const int tr = (t >> 4) * 4;
  float acc[4][4] = {{0.f}};
  for (int k = 0; k < 128; k += 4) {
    float4 xa[4], wb[4];
    #pragma unroll
    for (int i = 0; i < 4; ++i) xa[i] = *(const float4*)&xt[(tr + i) * 132 + k];
    #pragma unroll
    for (int j = 0; j < 4; ++j) wb[j] = *(const float4*)&Wt[(k + j) * 64 + tc];
    #pragma unroll
    for (int i = 0; i < 4; ++i) {
      const float* xp = (const float*)&xa[i];
      #pragma unroll
      for (int j = 0; j < 4; ++j) {
        const float* wp = (const float*)&wb[j];
        acc[i][0] += xp[j] * wp[0];
        acc[i][1] += xp[j] * wp[1];
        acc[i][2] += xp[j] * wp[2];
        acc[i][3] += xp[j] * wp[3];
      }
    }
  }
  #pragma unroll
  for (int i = 0; i < 4; ++i) {
    int row = row0 + tr + i;
    if (row < N_NODES) {
      __half2 p0 = __float22half2_rn(make_float2(acc[i][0], acc[i][1]));
      __half2 p1 = __float22half2_rn(make_float2(acc[i][2], acc[i][3]));
      uint2 pk = make_uint2(*(u32*)&p0, *(u32*)&p1);
      *(uint2*)(h1h + (size_t)row * 64 + tc) = pk;
    }
  }
}

// ---------------- fused: gather(h1) -> relu(.*norm_in + b1) -> @W2 * norm_out -> h2 ----
// one wave per node; 32 lanes per edge (u32 = 2 fp16 feats), 16-edge main block
__global__ __launch_bounds__(256) void k_gather_l1(const int* __restrict__ row_ptr,
                                                   const int* __restrict__ edge_src,
                                                   const __half* __restrict__ h1h,
                                                   const float* __restrict__ norm_in,
                                                   const float* __restrict__ norm_out,
                                                   const float* __restrict__ b1,
                                                   const float* __restrict__ W2,
                                                   __half* __restrict__ h2h) {
  __shared__ float W2s[64 * 17];   // padded stride 17
  const int t = threadIdx.x;
  for (int i = t; i < 64 * 16; i += 256) W2s[(i >> 4) * 17 + (i & 15)] = W2[i];
  __syncthreads();

  const int w = t >> 6;
  const int l = t & 63;
  const int n = blockIdx.x * 4 + w;
  const int half = l >> 5;         // which edge of each pair
  const u32 c = (u32)(l & 31);     // feature-pair index within row

  const u32* __restrict__ h1u = (const u32*)h1h;
  const int lo = row_ptr[n], hi = row_ptr[n + 1];

  float2 a0 = {0.f,0.f}, a1 = {0.f,0.f}, a2 = {0.f,0.f}, a3 = {0.f,0.f};
  float2 a4 = {0.f,0.f}, a5 = {0.f,0.f}, a6 = {0.f,0.f}, a7 = {0.f,0.f};
  int i = lo;
  // 16-edge main block: 8 independent lines in flight per wave
  for (; i + 16 <= hi; i += 16) {
    int sv = edge_src[i + (l & 15)];
    int s0 = __shfl(sv,  0 + half, 64);
    int s1 = __shfl(sv,  2 + half, 64);
    int s2 = __shfl(sv,  4 + half, 64);
    int s3 = __shfl(sv,  6 + half, 64);
    int s4 = __shfl(sv,  8 + half, 64);
    int s5 = __shfl(sv, 10 + half, 64);
    int s6 = __shfl(sv, 12 + half, 64);
    int s7 = __shfl(sv, 14 + half, 64);
    u32 v0 = h1u[(u32)s0 * 32u + c];
    u32 v1 = h1u[(u32)s1 * 32u + c];
    u32 v2 = h1u[(u32)s2 * 32u + c];
    u32 v3 = h1u[(u32)s3 * 32u + c];
    u32 v4 = h1u[(u32)s4 * 32u + c];
    u32 v5 = h1u[(u32)s5 * 32u + c];
    u32 v6 = h1u[(u32)s6 * 32u + c];
    u32 v7 = h1u[(u32)s7 * 32u + c];
    float2 f;
    f = __half22float2(*(__half2*)&v0); a0.x += f.x; a0.y += f.y;
    f = __half22float2(*(__half2*)&v1); a1.x += f.x; a1.y += f.y;
    f = __half22float2(*(__half2*)&v2); a2.x += f.x; a2.y += f.y;
    f = __half22float2(*(__half2*)&v3); a3.x += f.x; a3.y += f.y;
    f = __half22float2(*(__half2*)&v4); a4.x += f.x; a4.y += f.y;
    f = __half22float2(*(__half2*)&v5); a5.x += f.x; a5.y += f.y;
    f = __half22float2(*(__half2*)&v6); a6.x += f.x; a6.y += f.y;
    f = __half22float2(*(__half2*)&v7); a7.x += f.x; a7.y += f.y;
  }
  // 8-edge block
  if (i + 8 <= hi) {
    int sv = edge_src[i + (l & 7)];
    int s0 = __shfl(sv, 0 + half, 64);
    int s1 = __shfl(sv, 2 + half, 64);
    int s2 = __shfl(sv, 4 + half, 64);
    int s3 = __shfl(sv, 6 + half, 64);
    u32 v0 = h1u[(u32)s0 * 32u + c];
    u32 v1 = h1u[(u32)s1 * 32u + c];
    u32 v2 = h1u[(u32)s2 * 32u + c];
    u32 v3 = h1u[(u32)s3 * 32u + c];
    float2 f;
    f = __half22float2(*(__half2*)&v0); a0.x += f.x; a0.y += f.y;
    f = __half22float2(*(__half2*)&v1); a1.x += f.x; a1.y += f.y;
    f = __half22float2(*(__half2*)&v2); a2.x += f.x; a2.y += f.y;
    f = __half22float2(*(__half2*)&v3); a3.x += f.x; a3.y += f.y;
    i += 8;
  }
  // pairs
  for (; i + 2 <= hi; i += 2) {
    int s = edge_src[i + half];
    u32 v = h1u[(u32)s * 32u + c];
    float2 f = __half22float2(*(__half2*)&v);
    a0.x += f.x; a0.y += f.y;
  }
  if (i < hi && half == 0) {
    int s = edge_src[i];
    u32 v = h1u[(u32)s * 32u + c];
    float2 f = __half22float2(*(__half2*)&v);
    a0.x += f.x; a0.y += f.y;
  }
  float accx = ((a0.x + a1.x) + (a2.x + a3.x)) + ((a4.x + a5.x) + (a6.x + a7.x));
  float accy = ((a0.y + a1.y) + (a2.y + a3.y)) + ((a4.y + a5.y) + (a6.y + a7.y));
  accx += __shfl_xor(accx, 32, 64);
  accy += __shfl_xor(accy, 32, 64);

  const float ni = norm_in[n];
  const float2 bb = ((const float2*)b1)[c];
  float h1x = fmaxf(accx * ni + bb.x, 0.0f);
  float h1y = fmaxf(accy * ni + bb.y, 0.0f);

  const int j = l & 15, p = l >> 4;
  float partial = 0.f;
  #pragma unroll
  for (int kk = 0; kk < 16; kk += 2) {
    int sl = p * 8 + (kk >> 1);
    float vx = __shfl(h1x, sl, 64);
    float vy = __shfl(h1y, sl, 64);
    partial += vx * W2s[(p * 16 + kk) * 17 + j];
    partial += vy * W2s[(p * 16 + kk + 1) * 17 + j];
  }
  partial += __shfl_xor(partial, 16, 64);
  partial += __shfl_xor(partial, 32, 64);
  if (l < 16) h2h[(size_t)n * 16 + l] = __float2half(norm_out[n] * partial);
}

// ---------------- gather layer2: agg2 = norm_in * sum_edges h2[src]  (16 feats) --------
__global__ __launch_bounds__(256) void k_gather_l2(const int* __restrict__ row_ptr,
                                                   const int* __restrict__ edge_src,
                                                   const __half* __restrict__ h2h,
                                                   const float* __restrict__ norm_in,
                                                   float* __restrict__ agg2) {
  const int t = threadIdx.x;
  const int w = t >> 6;
  const int l = t & 63;
  const int n = blockIdx.x * 4 + w;
  const int f2 = l & 7;
  const int p = l >> 3;

  const u32* __restrict__ h2u = (const u32*)h2h;
  const int lo = row_ptr[n], hi = row_ptr[n + 1];

  float ax = 0.f, ay = 0.f, bx = 0.f, by = 0.f;
  int i = lo + p;
  for (; i + 8 < hi; i += 16) {
    int s0 = edge_src[i], s1 = edge_src[i + 8];
    u32 v0 = h2u[(u32)s0 * 8u + (u32)f2];
    u32 v1 = h2u[(u32)s1 * 8u + (u32)f2];
    float2 g0 = __half22float2(*(__half2*)&v0);
    float2 g1 = __half22float2(*(__half2*)&v1);
    ax += g0.x; ay += g0.y;
    bx += g1.x; by += g1.y;
  }
  if (i < hi) {
    int s = edge_src[i];
    u32 v = h2u[(u32)s * 8u + (u32)f2];
    float2 g = __half22float2(*(__half2*)&v);
    ax += g.x; ay += g.y;
  }
  float sx = ax + bx, sy = ay + by;
  sx += __shfl_xor(sx, 8, 64);  sy += __shfl_xor(sy, 8, 64);
  sx += __shfl_xor(sx, 16, 64); sy += __shfl_xor(sy, 16, 64);
  sx += __shfl_xor(sx, 32, 64); sy += __shfl_xor(sy, 32, 64);
  if (l < 8) {
    float ni = norm_in[n];
    ((float2*)agg2)[(size_t)n * 8 + f2] = make_float2(sx * ni, sy * ni);
  }
}

// ---------------- per-graph mean pool (gid sorted, no atomics) ----------------
__global__ __launch_bounds__(256) void k_pool(const float* __restrict__ agg2,
                                              const float* __restrict__ b2,
                                              const int* __restrict__ gid,
                                              float* __restrict__ out) {
  const int g = blockIdx.x;
  __shared__ int s_lo, s_hi;
  if (threadIdx.x == 0) {
    int a = 0, b = N_NODES;
    while (a < b) { int m = (a + b) >> 1; if (gid[m] < g) a = m + 1; else b = m; }
    s_lo = a;
    b = N_NODES;
    while (a < b) { int m = (a + b) >> 1; if (gid[m] < g + 1) a = m + 1; else b = m; }
    s_hi = a;
  }
  __syncthreads();
  const int lo = s_lo, hi = s_hi, cnt = hi - lo;
  const int j = threadIdx.x & 15;
  const int r = threadIdx.x >> 4;
  float acc = 0.f;
  for (int n = lo + r; n < hi; n += 16)
    acc += agg2[(size_t)n * 16 + j];

  __shared__ float red[256];
  red[threadIdx.x] = acc;
  __syncthreads();
  #pragma unroll
  for (int s = 8; s > 0; s >>= 1) {
    if (r < s) red[threadIdx.x] += red[threadIdx.x + s * 16];
    __syncthreads();
  }
  if (r == 0)
    out[g * 16 + j] = (cnt > 0) ? (red[j] / (float)cnt + b2[j]) : 0.0f;
}

extern "C" void kernel_launch(void* const* d_in, const int* in_sizes, int n_in,
                              void* d_out, int out_size, void* d_ws, size_t ws_size,
                              hipStream_t stream) {
  const float* x   = (const float*)d_in[0];
  const float* W1  = (const float*)d_in[1];
  const float* b1  = (const float*)d_in[2];
  const float* W2  = (const float*)d_in[3];
  const float* b2  = (const float*)d_in[4];
  const int*   src = (const int*)d_in[5];
  const int*   dst = (const int*)d_in[6];
  const int*   gid = (const int*)d_in[7];
  float* out = (float*)d_out;

  const size_t N = N_NODES, E = N_EDGES;
  float* wsf = (float*)d_ws;
  int*   wsi = (int*)d_ws;

  // persistent: norm_out, norm_in, row_ptr, edge_src
  float* norm_out = wsf;                                  // [N]
  float* norm_in  = wsf + N;                              // [N]
  int*   row_ptr  = wsi + 2 * N;                          // [N+1]
  int*   edge_src = wsi + 3 * N + 16;                     // [E]
  size_t S = 3 * N + 16 + E;                              // scratch base (words)
  // sort scratch (dead after k_outdeg; overlapped by h1h/h2h/agg2 afterwards)
  u8*    ssk8     = (u8*)(wsi + S);                       // [E bytes = E/4 words]
  int*   counts_d = wsi + S + E / 4;                      // [NBUCK*NBLK = 97750]
  int*   counts_s = wsi + S + E / 4 + 97752;              // [97750]
  int*   totals_d = wsi + S + E / 4 + 195504;             // [392]
  int*   totals_s = wsi + S + E / 4 + 195896;             // [392]
  int*   boff_d   = wsi + S + E / 4 + 196288;             // [392]
  int*   boff_s   = wsi + S + E / 4 + 196680;             // [392]
  u32*   ed       = (u32*)(wsi + S + E / 4 + 197072);     // [E]
  // reuse region (after CSR build):
  __half* h1h     = (__half*)(wsi + S);                   // [64N halves]
  __half* h2h     = (__half*)(wsi + S + 32 * N);          // [16N halves]
  float*  agg2    = (float*)(wsi + S + 40 * N);           // [16N]

  const int4* src4 = (const int4*)src;
  const int4* dst4 = (const int4*)dst;

  k_cnt       <<<NBLK, 256, 0, stream>>>(src4, dst4, counts_d, counts_s);
  k_scanA     <<<NBUCK, 256, 0, stream>>>(counts_d, counts_s, totals_d, totals_s);
  k_scanB     <<<1, 512, 0, stream>>>(totals_d, totals_s, boff_d, boff_s, row_ptr);
  k_scatter   <<<NBLK, 256, 0, stream>>>(src4, dst4, counts_d, counts_s, boff_d, boff_s, ed, ssk8);
  k_bucket_csr<<<NBUCK, 256, 0, stream>>>(ed, boff_d, row_ptr, norm_in, edge_src);
  k_outdeg    <<<NBUCK, 256, 0, stream>>>(ssk8, boff_s, norm_out);
  k_gemm1     <<<(N_NODES + 63) / 64, 256, 0, stream>>>(x, W1, norm_out, h1h);
  k_gather_l1 <<<N_NODES / 4, 256, 0, stream>>>(row_ptr, edge_src, h1h, norm_in, norm_out, b1, W2, h2h);
  k_gather_l2 <<<N_NODES / 4, 256, 0, stream>>>(row_ptr, edge_src, h2h, norm_in, agg2);
  k_pool      <<<N_GRAPHS, 256, 0, stream>>>(agg2, b2, gid, out);
}

// Round 8
// 285.338 us; speedup vs baseline: 4.4272x; 1.0811x over previous
//
#include <hip/hip_runtime.h>
#include <hip/hip_fp16.h>

#define N_NODES 100000
#define N_EDGES 1600000
#define N_GRAPHS 128
#define NBUCK 391            // ceil(100000/256) buckets of 256 nodes
#define NBLK 250             // blocks for count/scatter passes
#define CHUNK_E4 1600        // int4 elements per block (6400 edges)
#define LDX 136              // LDS stride (halves) for MFMA staging

typedef unsigned long long u64;
typedef unsigned int u32;
typedef unsigned char u8;
typedef _Float16 f16;
typedef f16 half8 __attribute__((ext_vector_type(8)));
typedef f16 half4v __attribute__((ext_vector_type(4)));
typedef float floatx4 __attribute__((ext_vector_type(4)));

// ---------------- pass 1: per-(bucket,block) counts of dst and src ----------------
__global__ __launch_bounds__(256) void k_cnt(const int4* __restrict__ src4,
                                             const int4* __restrict__ dst4,
                                             int* __restrict__ counts_d,
                                             int* __restrict__ counts_s) {
  __shared__ int hd[NBUCK], hs[NBUCK];
  const int t = threadIdx.x, blk = blockIdx.x;
  for (int j = t; j < NBUCK; j += 256) { hd[j] = 0; hs[j] = 0; }
  __syncthreads();
  const int start = blk * CHUNK_E4, end = start + CHUNK_E4;
  for (int i = start + t; i < end; i += 256) {
    int4 d = dst4[i]; int4 s = src4[i];
    atomicAdd(&hd[d.x >> 8], 1); atomicAdd(&hd[d.y >> 8], 1);
    atomicAdd(&hd[d.z >> 8], 1); atomicAdd(&hd[d.w >> 8], 1);
    atomicAdd(&hs[s.x >> 8], 1); atomicAdd(&hs[s.y >> 8], 1);
    atomicAdd(&hs[s.z >> 8], 1); atomicAdd(&hs[s.w >> 8], 1);
  }
  __syncthreads();
  for (int j = t; j < NBUCK; j += 256) {
    counts_d[j * NBLK + blk] = hd[j];
    counts_s[j * NBLK + blk] = hs[j];
  }
}

// ---------------- pass 2a: per-bucket exclusive scan over blocks ----------------
__global__ __launch_bounds__(256) void k_scanA(int* __restrict__ counts_d,
                                               int* __restrict__ counts_s,
                                               int* __restrict__ totals_d,
                                               int* __restrict__ totals_s) {
  __shared__ int s[256];
  const int b = blockIdx.x, t = threadIdx.x;
  int v = (t < NBLK) ? counts_d[b * NBLK + t] : 0;
  s[t] = v;
  __syncthreads();
  for (int off = 1; off < 256; off <<= 1) {
    int a = (t >= off) ? s[t - off] : 0;
    __syncthreads(); s[t] += a; __syncthreads();
  }
  if (t < NBLK) counts_d[b * NBLK + t] = s[t] - v;
  if (t == 255) totals_d[b] = s[t];
  __syncthreads();
  v = (t < NBLK) ? counts_s[b * NBLK + t] : 0;
  s[t] = v;
  __syncthreads();
  for (int off = 1; off < 256; off <<= 1) {
    int a = (t >= off) ? s[t - off] : 0;
    __syncthreads(); s[t] += a; __syncthreads();
  }
  if (t < NBLK) counts_s[b * NBLK + t] = s[t] - v;
  if (t == 255) totals_s[b] = s[t];
}

// ---------------- pass 2b: exclusive scan over buckets ----------------
__global__ __launch_bounds__(512) void k_scanB(const int* __restrict__ totals_d,
                                               const int* __restrict__ totals_s,
                                               int* __restrict__ boff_d,
                                               int* __restrict__ boff_s,
                                               int* __restrict__ row_ptr) {
  __shared__ int s[512];
  const int t = threadIdx.x;
  int v = (t < NBUCK) ? totals_d[t] : 0;
  s[t] = v;
  __syncthreads();
  for (int off = 1; off < 512; off <<= 1) {
    int a = (t >= off) ? s[t - off] : 0;
    __syncthreads(); s[t] += a; __syncthreads();
  }
  if (t < NBUCK) boff_d[t] = s[t] - v;
  if (t == 0) { boff_d[NBUCK] = N_EDGES; row_ptr[N_NODES] = N_EDGES; }
  __syncthreads();
  v = (t < NBUCK) ? totals_s[t] : 0;
  s[t] = v;
  __syncthreads();
  for (int off = 1; off < 512; off <<= 1) {
    int a = (t >= off) ? s[t - off] : 0;
    __syncthreads(); s[t] += a; __syncthreads();
  }
  if (t < NBUCK) boff_s[t] = s[t] - v;
  if (t == 0) boff_s[NBUCK] = N_EDGES;
}

// ---------------- pass 3: bucket-scatter packed (dl,src) u32 and src low-bytes ------
__global__ __launch_bounds__(256) void k_scatter(const int4* __restrict__ src4,
                                                 const int4* __restrict__ dst4,
                                                 const int* __restrict__ counts_d,
                                                 const int* __restrict__ counts_s,
                                                 const int* __restrict__ boff_d,
                                                 const int* __restrict__ boff_s,
                                                 u32* __restrict__ ed,
                                                 u8* __restrict__ ssk8) {
  __shared__ int cur_d[NBUCK], cur_s[NBUCK];
  const int t = threadIdx.x, blk = blockIdx.x;
  for (int j = t; j < NBUCK; j += 256) {
    cur_d[j] = boff_d[j] + counts_d[j * NBLK + blk];
    cur_s[j] = boff_s[j] + counts_s[j * NBLK + blk];
  }
  __syncthreads();
  const int start = blk * CHUNK_E4, end = start + CHUNK_E4;
  for (int i = start + t; i < end; i += 256) {
    int4 d4 = dst4[i]; int4 s4 = src4[i];
    {
      int d = d4.x, s = s4.x;
      int pd = atomicAdd(&cur_d[d >> 8], 1);
      ed[pd] = ((u32)(d & 255) << 24) | (u32)s;
      int ps = atomicAdd(&cur_s[s >> 8], 1);
      ssk8[ps] = (u8)(s & 255);
    }
    {
      int d = d4.y, s = s4.y;
      int pd = atomicAdd(&cur_d[d >> 8], 1);
      ed[pd] = ((u32)(d & 255) << 24) | (u32)s;
      int ps = atomicAdd(&cur_s[s >> 8], 1);
      ssk8[ps] = (u8)(s & 255);
    }
    {
      int d = d4.z, s = s4.z;
      int pd = atomicAdd(&cur_d[d >> 8], 1);
      ed[pd] = ((u32)(d & 255) << 24) | (u32)s;
      int ps = atomicAdd(&cur_s[s >> 8], 1);
      ssk8[ps] = (u8)(s & 255);
    }
    {
      int d = d4.w, s = s4.w;
      int pd = atomicAdd(&cur_d[d >> 8], 1);
      ed[pd] = ((u32)(d & 255) << 24) | (u32)s;
      int ps = atomicAdd(&cur_s[s >> 8], 1);
      ssk8[ps] = (u8)(s & 255);
    }
  }
}

// ------ pass 4: per-bucket CSR finalize + out-degree (fused; both partitioned by bucket) ----
__global__ __launch_bounds__(256) void k_bucket_csr(const u32* __restrict__ ed,
                                                    const int* __restrict__ boff_d,
                                                    const u8* __restrict__ ssk8,
                                                    const int* __restrict__ boff_s,
                                                    int* __restrict__ row_ptr,
                                                    float* __restrict__ norm_in,
                                                    float* __restrict__ norm_out,
                                                    int* __restrict__ edge_src) {
  __shared__ int hist[256], scanbuf[256], cursor[256], hist2[256];
  const int b = blockIdx.x, t = threadIdx.x;
  const int base = b << 8;
  hist[t] = 0; hist2[t] = 0;
  __syncthreads();
  const int slo = boff_s[b], shi = boff_s[b + 1];
  for (int i = slo + t; i < shi; i += 256)
    atomicAdd(&hist2[ssk8[i]], 1);
  const int lo = boff_d[b], hi = boff_d[b + 1];
  for (int i = lo + t; i < hi; i += 256)
    atomicAdd(&hist[ed[i] >> 24], 1);
  __syncthreads();
  int node = base + t;
  if (node < N_NODES)
    norm_out[node] = rsqrtf(fmaxf((float)hist2[t], 1.0f));
  int v = hist[t];
  scanbuf[t] = v;
  __syncthreads();
  for (int off = 1; off < 256; off <<= 1) {
    int a = (t >= off) ? scanbuf[t - off] : 0;
    __syncthreads(); scanbuf[t] += a; __syncthreads();
  }
  int excl = scanbuf[t] - v;
  if (node < N_NODES) {
    row_ptr[node] = lo + excl;
    norm_in[node] = rsqrtf(fmaxf((float)v, 1.0f));
  }
  cursor[t] = excl;
  __syncthreads();
  for (int i = lo + t; i < hi; i += 256) {
    u32 e = ed[i];
    int p = atomicAdd(&cursor[e >> 24], 1);
    edge_src[lo + p] = (int)(e & 0x00FFFFFFu);
  }
}

// ---------------- gemm1 (MFMA fp16): h1 = (x * norm_out) @ W1 -> fp16 -------------------
// 64 rows/block, 4 waves; wave = 16 rows x 64 cols via 4 C-frags, K=128 in 4 MFMA steps.
// A[m=lane&15][k=quad*8+j]; B[n=lane&15][k] (W1^T in LDS); C/D col=lane&15,row=quad*4+reg.
__global__ __launch_bounds__(256) void k_gemm1(const float* __restrict__ x,
                                               const float* __restrict__ W1,
                                               const float* __restrict__ norm_out,
                                               __half* __restrict__ h1h) {
  __shared__ __align__(16) f16 Xs[64 * LDX];
  __shared__ __align__(16) f16 Ws[64 * LDX];
  const int t = threadIdx.x;
  const int row0 = blockIdx.x * 64;

  // stage W1^T: W1 [128][64] fp32 -> Ws[n][k] fp16
  const float4* W4 = (const float4*)W1;     // 2048 float4 = [k][n4]
  for (int i = t; i < 2048; i += 256) {
    int k = i >> 4, n4 = (i & 15) * 4;
    float4 v = W4[i];
    Ws[(n4 + 0) * LDX + k] = (f16)v.x;
    Ws[(n4 + 1) * LDX + k] = (f16)v.y;
    Ws[(n4 + 2) * LDX + k] = (f16)v.z;
    Ws[(n4 + 3) * LDX + k] = (f16)v.w;
  }
  // stage 64 rows of x, scaled by norm_out, fp16 (zeros for rows >= N_NODES -> dummy row)
  const float4* x4 = (const float4*)x;
  #pragma unroll
  for (int i = 0; i < 8; ++i) {
    int idx = t + 256 * i;                  // 0..2047
    int r = idx >> 5, c4 = idx & 31;
    int row = row0 + r;
    float4 v = make_float4(0.f, 0.f, 0.f, 0.f);
    if (row < N_NODES) {
      float s = norm_out[row];
      v = x4[(size_t)row * 32 + c4];
      v.x *= s; v.y *= s; v.z *= s; v.w *= s;
    }
    half4v h = { (f16)v.x, (f16)v.y, (f16)v.z, (f16)v.w };
    *(half4v*)&Xs[r * LDX + c4 * 4] = h;
  }
  __syncthreads();

  const int w = t >> 6, l = t & 63;
  const int m = l & 15, quad = l >> 4;
  floatx4 c0 = {0.f,0.f,0.f,0.f}, c1 = {0.f,0.f,0.f,0.f};
  floatx4 c2 = {0.f,0.f,0.f,0.f}, c3 = {0.f,0.f,0.f,0.f};
  const f16* xrow = &Xs[(w * 16 + m) * LDX + quad * 8];
  const f16* wrow = &Ws[m * LDX + quad * 8];
  #pragma unroll
  for (int kb = 0; kb < 4; ++kb) {
    half8 a  = *(const half8*)(xrow + kb * 32);
    half8 b0 = *(const half8*)(wrow + kb * 32);
    half8 b1 = *(const half8*)(wrow + 16 * LDX + kb * 32);
    half8 b2 = *(const half8*)(wrow + 32 * LDX + kb * 32);
    half8 b3 = *(const half8*)(wrow + 48 * LDX + kb * 32);
    c0 = __builtin_amdgcn_mfma_f32_16x16x32_f16(a, b0, c0, 0, 0, 0);
    c1 = __builtin_amdgcn_mfma_f32_16x16x32_f16(a, b1, c1, 0, 0, 0);
    c2 = __builtin_amdgcn_mfma_f32_16x16x32_f16(a, b2, c2, 0, 0, 0);
    c3 = __builtin_amdgcn_mfma_f32_16x16x32_f16(a, b3, c3, 0, 0, 0);
  }
  #pragma unroll
  for (int r = 0; r < 4; ++r) {
    int row = row0 + w * 16 + quad * 4 + r;
    if (row < N_NODES + 1) {                // include zeros dummy row N_NODES
      __half* dst = h1h + (size_t)row * 64 + m;
      dst[0]  = __float2half(c0[r]);
      dst[16] = __float2half(c1[r]);
      dst[32] = __float2half(c2[r]);
      dst[48] = __float2half(c3[r]);
    }
  }
}

// ---------------- fused: gather(h1) -> relu(.*norm_in + b1) -> @W2 * norm_out -> h2 ----
// one wave per node; 32 lanes/edge (u32 = 2 fp16 feats); uniform clamped 16-edge blocks
__global__ __launch_bounds__(256) void k_gather_l1(const int* __restrict__ row_ptr,
                                                   const int* __restrict__ edge_src,
                                                   const __half* __restrict__ h1h,
                                                   const float* __restrict__ norm_in,
                                                   const float* __restrict__ norm_out,
                                                   const float* __restrict__ b1,
                                                   const float* __restrict__ W2,
                                                   __half* __restrict__ h2h) {
  __shared__ float W2s[64 * 17];   // padded stride 17
  const int t = threadIdx.x;
  for (int i = t; i < 64 * 16; i += 256) W2s[(i >> 4) * 17 + (i & 15)] = W2[i];
  if (blockIdx.x == 0 && t < 16) h2h[(size_t)N_NODES * 16 + t] = __float2half(0.f);
  __syncthreads();

  const int w = t >> 6;
  const int l = t & 63;
  const int n = blockIdx.x * 4 + w;
  const int hf = l >> 5;           // which edge of each pair
  const u32 c = (u32)(l & 31);     // feature-pair index within row

  const u32* __restrict__ h1u = (const u32*)h1h;
  const int lo = row_ptr[n], hi = row_ptr[n + 1];

  float2 a0 = {0.f,0.f}, a1 = {0.f,0.f}, a2 = {0.f,0.f}, a3 = {0.f,0.f};
  float2 a4 = {0.f,0.f}, a5 = {0.f,0.f}, a6 = {0.f,0.f}, a7 = {0.f,0.f};
  for (int i = lo; i < hi; i += 16) {
    int idx = i + (l & 15);
    int sv = (idx < hi) ? edge_src[idx] : (int)N_NODES;   // clamp to zeros row
    int s0 = __shfl(sv,  0 + hf, 64);
    int s1 = __shfl(sv,  2 + hf, 64);
    int s2 = __shfl(sv,  4 + hf, 64);
    int s3 = __shfl(sv,  6 + hf, 64);
    int s4 = __shfl(sv,  8 + hf, 64);
    int s5 = __shfl(sv, 10 + hf, 64);
    int s6 = __shfl(sv, 12 + hf, 64);
    int s7 = __shfl(sv, 14 + hf, 64);
    u32 v0 = h1u[(u32)s0 * 32u + c];
    u32 v1 = h1u[(u32)s1 * 32u + c];
    u32 v2 = h1u[(u32)s2 * 32u + c];
    u32 v3 = h1u[(u32)s3 * 32u + c];
    u32 v4 = h1u[(u32)s4 * 32u + c];
    u32 v5 = h1u[(u32)s5 * 32u + c];
    u32 v6 = h1u[(u32)s6 * 32u + c];
    u32 v7 = h1u[(u32)s7 * 32u + c];
    float2 f;
    f = __half22float2(*(__half2*)&v0); a0.x += f.x; a0.y += f.y;
    f = __half22float2(*(__half2*)&v1); a1.x += f.x; a1.y += f.y;
    f = __half22float2(*(__half2*)&v2); a2.x += f.x; a2.y += f.y;
    f = __half22float2(*(__half2*)&v3); a3.x += f.x; a3.y += f.y;
    f = __half22float2(*(__half2*)&v4); a4.x += f.x; a4.y += f.y;
    f = __half22float2(*(__half2*)&v5); a5.x += f.x; a5.y += f.y;
    f = __half22float2(*(__half2*)&v6); a6.x += f.x; a6.y += f.y;
    f = __half22float2(*(__half2*)&v7); a7.x += f.x; a7.y += f.y;
  }
  float accx = ((a0.x + a1.x) + (a2.x + a3.x)) + ((a4.x + a5.x) + (a6.x + a7.x));
  float accy = ((a0.y + a1.y) + (a2.y + a3.y)) + ((a4.y + a5.y) + (a6.y + a7.y));
  accx += __shfl_xor(accx, 32, 64);
  accy += __shfl_xor(accy, 32, 64);

  const float ni = norm_in[n];
  const float2 bb = ((const float2*)b1)[c];
  float h1x = fmaxf(accx * ni + bb.x, 0.0f);
  float h1y = fmaxf(accy * ni + bb.y, 0.0f);

  const int j = l & 15, p = l >> 4;
  float partial = 0.f;
  #pragma unroll
  for (int kk = 0; kk < 16; kk += 2) {
    int sl = p * 8 + (kk >> 1);
    float vx = __shfl(h1x, sl, 64);
    float vy = __shfl(h1y, sl, 64);
    partial += vx * W2s[(p * 16 + kk) * 17 + j];
    partial += vy * W2s[(p * 16 + kk + 1) * 17 + j];
  }
  partial += __shfl_xor(partial, 16, 64);
  partial += __shfl_xor(partial, 32, 64);
  if (l < 16) h2h[(size_t)n * 16 + l] = __float2half(norm_out[n] * partial);
}

// ---------------- gather layer2: agg2 = norm_in * sum_edges h2[src]  (16 feats) --------
// 8 lanes/edge (u32 loads); uniform clamped 16-edge blocks
__global__ __launch_bounds__(256) void k_gather_l2(const int* __restrict__ row_ptr,
                                                   const int* __restrict__ edge_src,
                                                   const __half* __restrict__ h2h,
                                                   const float* __restrict__ norm_in,
                                                   float* __restrict__ agg2) {
  const int t = threadIdx.x;
  const int w = t >> 6;
  const int l = t & 63;
  const int n = blockIdx.x * 4 + w;
  const int f2 = l & 7;
  const int p = l >> 3;            // 8 edge slices

  const u32* __restrict__ h2u = (const u32*)h2h;
  const int lo = row_ptr[n], hi = row_ptr[n + 1];

  float ax = 0.f, ay = 0.f, bx = 0.f, by = 0.f;
  for (int base = lo; base < hi; base += 16) {
    int i1 = base + p, i2 = base + p + 8;
    int s0 = (i1 < hi) ? edge_src[i1] : (int)N_NODES;
    int s1 = (i2 < hi) ? edge_src[i2] : (int)N_NODES;
    u32 v0 = h2u[(u32)s0 * 8u + (u32)f2];
    u32 v1 = h2u[(u32)s1 * 8u + (u32)f2];
    float2 g0 = __half22float2(*(__half2*)&v0);
    float2 g1 = __half22float2(*(__half2*)&v1);
    ax += g0.x; ay += g0.y;
    bx += g1.x; by += g1.y;
  }
  float sx = ax + bx, sy = ay + by;
  sx += __shfl_xor(sx, 8, 64);  sy += __shfl_xor(sy, 8, 64);
  sx += __shfl_xor(sx, 16, 64); sy += __shfl_xor(sy, 16, 64);
  sx += __shfl_xor(sx, 32, 64); sy += __shfl_xor(sy, 32, 64);
  if (l < 8) {
    float ni = norm_in[n];
    ((float2*)agg2)[(size_t)n * 8 + f2] = make_float2(sx * ni, sy * ni);
  }
}

// ---------------- per-graph mean pool (gid sorted, no atomics) ----------------
__global__ __launch_bounds__(256) void k_pool(const float* __restrict__ agg2,
                                              const float* __restrict__ b2,
                                              const int* __restrict__ gid,
                                              float* __restrict__ out) {
  const int g = blockIdx.x;
  __shared__ int s_lo, s_hi;
  if (threadIdx.x == 0) {
    int a = 0, b = N_NODES;
    while (a < b) { int m = (a + b) >> 1; if (gid[m] < g) a = m + 1; else b = m; }
    s_lo = a;
    b = N_NODES;
    while (a < b) { int m = (a + b) >> 1; if (gid[m] < g + 1) a = m + 1; else b = m; }
    s_hi = a;
  }
  __syncthreads();
  const int lo = s_lo, hi = s_hi, cnt = hi - lo;
  const int j = threadIdx.x & 15;
  const int r = threadIdx.x >> 4;
  float acc = 0.f;
  for (int n = lo + r; n < hi; n += 16)
    acc += agg2[(size_t)n * 16 + j];

  __shared__ float red[256];
  red[threadIdx.x] = acc;
  __syncthreads();
  #pragma unroll
  for (int s = 8; s > 0; s >>= 1) {
    if (r < s) red[threadIdx.x] += red[threadIdx.x + s * 16];
    __syncthreads();
  }
  if (r == 0)
    out[g * 16 + j] = (cnt > 0) ? (red[j] / (float)cnt + b2[j]) : 0.0f;
}

extern "C" void kernel_launch(void* const* d_in, const int* in_sizes, int n_in,
                              void* d_out, int out_size, void* d_ws, size_t ws_size,
                              hipStream_t stream) {
  const float* x   = (const float*)d_in[0];
  const float* W1  = (const float*)d_in[1];
  const float* b1  = (const float*)d_in[2];
  const float* W2  = (const float*)d_in[3];
  const float* b2  = (const float*)d_in[4];
  const int*   src = (const int*)d_in[5];
  const int*   dst = (const int*)d_in[6];
  const int*   gid = (const int*)d_in[7];
  float* out = (float*)d_out;

  const size_t N = N_NODES, E = N_EDGES;
  float* wsf = (float*)d_ws;
  int*   wsi = (int*)d_ws;

  // persistent: norm_out, norm_in, row_ptr, edge_src
  float* norm_out = wsf;                                  // [N]
  float* norm_in  = wsf + N;                              // [N]
  int*   row_ptr  = wsi + 2 * N;                          // [N+1]
  int*   edge_src = wsi + 3 * N + 16;                     // [E]
  size_t S = 3 * N + 16 + E;                              // scratch base (words)
  // sort scratch (dead after k_bucket_csr; overlapped by h1h/h2h/agg2 afterwards)
  u8*    ssk8     = (u8*)(wsi + S);                       // [E bytes]
  int*   counts_d = wsi + S + E / 4;                      // [NBUCK*NBLK = 97750]
  int*   counts_s = wsi + S + E / 4 + 97752;              // [97750]
  int*   totals_d = wsi + S + E / 4 + 195504;             // [392]
  int*   totals_s = wsi + S + E / 4 + 195896;             // [392]
  int*   boff_d   = wsi + S + E / 4 + 196288;             // [392]
  int*   boff_s   = wsi + S + E / 4 + 196680;             // [392]
  u32*   ed       = (u32*)(wsi + S + E / 4 + 197072);     // [E]
  // reuse region (after CSR build); h1h/h2h have a zeros dummy row at index N
  __half* h1h     = (__half*)(wsi + S);                   // [64*(N+1) halves]
  __half* h2h     = (__half*)(wsi + S + 32 * N + 40);     // [16*(N+1) halves]
  float*  agg2    = (float*)(wsi + S + 40 * N + 56);      // [16N]

  const int4* src4 = (const int4*)src;
  const int4* dst4 = (const int4*)dst;

  k_cnt       <<<NBLK, 256, 0, stream>>>(src4, dst4, counts_d, counts_s);
  k_scanA     <<<NBUCK, 256, 0, stream>>>(counts_d, counts_s, totals_d, totals_s);
  k_scanB     <<<1, 512, 0, stream>>>(totals_d, totals_s, boff_d, boff_s, row_ptr);
  k_scatter   <<<NBLK, 256, 0, stream>>>(src4, dst4, counts_d, counts_s, boff_d, boff_s, ed, ssk8);
  k_bucket_csr<<<NBUCK, 256, 0, stream>>>(ed, boff_d, ssk8, boff_s, row_ptr, norm_in, norm_out, edge_src);
  k_gemm1     <<<(N_NODES + 64) / 64, 256, 0, stream>>>(x, W1, norm_out, h1h);
  k_gather_l1 <<<N_NODES / 4, 256, 0, stream>>>(row_ptr, edge_src, h1h, norm_in, norm_out, b1, W2, h2h);
  k_gather_l2 <<<N_NODES / 4, 256, 0, stream>>>(row_ptr, edge_src, h2h, norm_in, agg2);
  k_pool      <<<N_GRAPHS, 256, 0, stream>>>(agg2, b2, gid, out);
}